// Round 12
// baseline (717.724 us; speedup 1.0000x reference)
//
#include <hip/hip_runtime.h>
#include <math.h>

typedef short bf16x8 __attribute__((ext_vector_type(8)));
typedef float f32x4 __attribute__((ext_vector_type(4)));

// workspace layout (float offsets)
#define WS_B0   0u
#define WS_B1   4194304u
#define WS_K    8388608u
#define WS_V    16777216u
#define WS_ATTN 25165824u
#define WS_PART 26083328u
#define WS_ZP   26312704u
#define WS_SLOT 26327040u
#define WS_ROW  26341376u
#define SCALE_ 0.125f

#define OFF_PEB   0u
#define OFF_WCLS  160000u
#define OFF_S     180000u
#define OFF_ZB    250000u

__device__ __forceinline__ float wave_sum(float v) {
#pragma unroll
    for (int m = 32; m >= 1; m >>= 1) v += __shfl_xor(v, m, 64);
    return v;
}
__device__ __forceinline__ unsigned short f2bf(float f) {
    unsigned u = __float_as_uint(f);
    u = u + 0x7fffu + ((u >> 16) & 1u);
    return (unsigned short)(u >> 16);
}
__device__ __forceinline__ float bf2f(unsigned short h) {
    return __uint_as_float(((unsigned)h) << 16);
}
__device__ __forceinline__ void gl_lds16(const void* src, void* lds_base) {
    __builtin_amdgcn_global_load_lds(
        (const __attribute__((address_space(1))) unsigned int*)src,
        (__attribute__((address_space(3))) unsigned int*)lds_base,
        16, 0, 0);
}

// ---------------- weight packing (device helper, B-fragment order) ----------------
__device__ __forceinline__ void pack_one(
    const float* __restrict__ w, unsigned short* __restrict__ wp,
    int CIN, int COUT_STORE, int KS, int NT, int t)
{
    int lane = t & 63;
    int nt = (t >> 6) % NT;
    int ch = t / (64 * NT);
    int CPT = CIN / 32;
    int cic = ch % CPT;
    int tap = ch / CPT;
    int ky = tap / KS, kx = tap % KS;
    int co = nt * 16 + (lane & 15);
    int k0 = cic * 32 + (lane >> 4) * 8;
    unsigned short v[8];
#pragma unroll
    for (int j = 0; j < 8; ++j) {
        int ci = k0 + j;
        float f = (co < COUT_STORE) ? w[((size_t)(co * CIN + ci) * KS + ky) * KS + kx] : 0.f;
        v[j] = f2bf(f);
    }
    *(uint4*)(wp + (size_t)t * 8) = *(uint4*)v;
}

// ---------------- encoder-side packing: 3 convs + 4 fc mats + zero page ----------------
__global__ __launch_bounds__(256) void pack_enc(
    const float* __restrict__ ec2w, const float* __restrict__ ec3w,
    const float* __restrict__ ec4w, unsigned short* __restrict__ wp,
    const float* __restrict__ fc1w, const float* __restrict__ fc2w,
    const float* __restrict__ kw, const float* __restrict__ vw,
    unsigned short* __restrict__ pfc, float* __restrict__ zpage)
{
    if (blockIdx.x == 0 && threadIdx.x < 64) zpage[threadIdx.x] = 0.f;
    int t = blockIdx.x * 256 + threadIdx.x;
    if (t < 38400) {
        int which = t / 12800;
        int tt = t % 12800;
        const float* w = (which == 0) ? ec2w : ((which == 1) ? ec3w : ec4w);
        pack_one(w, wp + (size_t)which * 102400, 64, 64, 5, 4, tt);
        return;
    }
    t -= 38400;
    if (t < 2048) {
        int which = t / 512;
        int tt = t % 512;
        const float* w = (which == 0) ? fc1w : ((which == 1) ? fc2w : ((which == 2) ? kw : vw));
        unsigned short* dst = pfc + (size_t)which * 4096;
        int lane = tt & 63;
        int nt = (tt >> 6) & 3;
        int ck = tt >> 8;
        int n = nt * 16 + (lane & 15);
        int k0 = ck * 32 + (lane >> 4) * 8;
        unsigned short v[8];
#pragma unroll
        for (int j = 0; j < 8; ++j) v[j] = f2bf(w[(size_t)(k0 + j) * 64 + n]);
        *(uint4*)(dst + (size_t)tt * 8) = *(uint4*)v;
    }
}

// ---------------- decoder prep: packs + pe field + slot copy + zeroes ----------------
__global__ __launch_bounds__(256) void dec_prep(
    const float* __restrict__ dc1w, const float* __restrict__ dc2w,
    const float* __restrict__ dc3w, const float* __restrict__ dc4w,
    unsigned short* __restrict__ p_dc1, unsigned short* __restrict__ p_dc2,
    unsigned short* __restrict__ p_dc3, unsigned short* __restrict__ p_dc4,
    const float* __restrict__ dpw, const float* __restrict__ dpb,
    unsigned short* __restrict__ peb, float* __restrict__ zbias,
    const float* __restrict__ slots, float* __restrict__ out)
{
    int t = blockIdx.x * 256 + threadIdx.x;
    if (t < 6400) { pack_one(dc1w, p_dc1, 64, 32, 5, 2, t); return; }
    t -= 6400;
    if (t < 3200) { pack_one(dc2w, p_dc2, 32, 32, 5, 2, t); return; }
    t -= 3200;
    if (t < 3200) { pack_one(dc3w, p_dc3, 32, 32, 5, 2, t); return; }
    t -= 3200;
    if (t < 576)  { pack_one(dc4w, p_dc4, 32, 4, 3, 1, t); return; }
    t -= 576;
    if (t < 4900) {
        const int iy = t / 70, ix = t % 70;
        const float fy = iy * (1.f / 69.f), fx = ix * (1.f / 69.f);
        unsigned short v[64];
#pragma unroll
        for (int ci = 0; ci < 64; ++ci) {
            float p = (1.f - fy) * dpw[ci] + fy * dpw[64 + ci]
                    + fx * dpw[128 + ci] + (1.f - fx) * dpw[192 + ci] + dpb[ci];
            v[ci] = f2bf(p);
        }
        uint4* ob = (uint4*)(peb + (size_t)t * 64);
#pragma unroll
        for (int i = 0; i < 8; ++i) ob[i] = ((uint4*)v)[i];
        return;
    }
    t -= 4900;
    if (t < 14336) { out[3670017 + t] = slots[t]; return; }
    t -= 14336;
    if (t < 32) zbias[t] = 0.f;
    else if (t == 32) out[0] = 0.f;
}

// ---------------- Wcls[9][32][64] ----------------
__global__ __launch_bounds__(256) void wcls_build(
    const float* __restrict__ w, float* __restrict__ wcls)
{
    int idx = blockIdx.x * 256 + threadIdx.x;
    if (idx >= 9 * 32 * 64) return;
    int cls = idx / (32 * 64);
    int co = (idx / 64) % 32;
    int ci = idx % 64;
    int rc = cls / 3, cc = cls % 3;
    int ky0 = (rc == 0) ? 1 : 0, ky1 = (rc == 2) ? 3 : 4;
    int kx0 = (cc == 0) ? 1 : 0, kx1 = (cc == 2) ? 3 : 4;
    float s = 0.f;
    const float* wb = w + (size_t)(co * 64 + ci) * 25;
    for (int ky = ky0; ky <= ky1; ++ky)
        for (int kx = kx0; kx <= kx1; ++kx)
            s += wb[ky * 5 + kx];
    wcls[idx] = s;
}

// ---------------- S[224][9][32] = slots @ Wcls^T ----------------
__global__ __launch_bounds__(256) void slot_s(
    const float* __restrict__ slots, const float* __restrict__ wcls,
    float* __restrict__ S)
{
    int idx = blockIdx.x * 256 + threadIdx.x;
    if (idx >= 224 * 9 * 32) return;
    int n = idx / (9 * 32);
    int cls = (idx / 32) % 9;
    int co = idx % 32;
    const float* sl = slots + n * 64;
    const float* wc = wcls + (size_t)(cls * 32 + co) * 64;
    float s = 0.f;
#pragma unroll
    for (int ci = 0; ci < 64; ++ci) s = fmaf(sl[ci], wc[ci], s);
    S[idx] = s;
}

// ---------------- MFMA implicit-GEMM conv, per-K-slice DMA-staged LDS ----------------
// Tile holds ONE 32-channel K-slice (TH*TH*32 bf16 = 25.6KB max) -> 6 blocks/CU.
// Per cic: DMA-stage slice, barrier, kx-loop compute, barrier. Chunk-linear
// swizzled layout (chunkpos = (g + c) & 3), proven conflict-free.
template<int CIN, int NTT, int NTU, int KS, int PAD, int NSTORE, int RELU, int OUTF32>
__global__ __launch_bounds__(256) void conv_mfma(
    const unsigned short* __restrict__ in, const unsigned short* __restrict__ wpack,
    const float* __restrict__ bias, void* __restrict__ outv,
    const unsigned short* __restrict__ zpage,
    int Hin, int Win, int Hout, int Wout, int tilesX, int tilesY)
{
    constexpr int TS = 16, TH = TS + KS - 1;
    constexpr int CPT = CIN / 32;
    constexpr int CS = NTT / NTU;
    constexpr int TOTCH = TH * TH * 4;                 // chunks per 32-ch slice
    __shared__ __align__(16) unsigned short tile[TOTCH * 8];
    const int tpb = tilesX * tilesY;
    const int blk = blockIdx.x;
    const int n = blk / (tpb * CS);
    const int rem = blk % (tpb * CS);
    const int t = rem / CS;
    const int cog = rem % CS;
    const int ntb = cog * NTU;
    const int ty0 = (t / tilesX) * TS, tx0 = (t % tilesX) * TS;
    const int tid = threadIdx.x;
    const int wv = tid >> 6, lane = tid & 63;
    const int q = lane >> 4, m = lane & 15;
    const int row0 = wv * 4;

    const unsigned short* inb = in + (size_t)n * Hin * Win * CIN;

    f32x4 acc[4][NTU];
#pragma unroll
    for (int mt = 0; mt < 4; ++mt)
#pragma unroll
        for (int nt = 0; nt < NTU; ++nt) acc[mt][nt] = (f32x4){0.f, 0.f, 0.f, 0.f};

#pragma unroll
    for (int cic = 0; cic < CPT; ++cic) {
        // ---- stage this 32-channel slice via global_load_lds ----
        for (int cb = wv * 64; cb < TOTCH; cb += 256) {
            const int idx = cb + lane;
            const int r = idx / (TH * 4);
            const int p = idx % (TH * 4);
            const int c = p / 4;
            const int chunk = p & 3;
            const int g = (chunk - c) & 3;              // channel-group within slice
            const int iy = ty0 - PAD + r, ix = tx0 - PAD + c;
            const bool ok = (idx < TOTCH) && ((unsigned)iy < (unsigned)Hin) && ((unsigned)ix < (unsigned)Win);
            const unsigned short* src = ok ?
                (inb + ((size_t)iy * Win + ix) * CIN + cic * 32 + g * 8) : zpage;
            gl_lds16(src, tile + (size_t)cb * 8);
        }
        __syncthreads();

#pragma unroll
        for (int kx = 0; kx < KS; ++kx) {
            bf16x8 B[KS][NTU];
#pragma unroll
            for (int ky = 0; ky < KS; ++ky)
#pragma unroll
                for (int nt = 0; nt < NTU; ++nt)
                    B[ky][nt] = *(const bf16x8*)(wpack +
                        ((size_t)(((ky * KS + kx) * CPT + cic) * NTT + ntb + nt) * 64 + lane) * 8);
            const int cbase = m + kx;
            const int slot = (q * 8 + cbase * 8) & 31;
#pragma unroll
            for (int ir = 0; ir < KS + 3; ++ir) {
                bf16x8 afr = *(const bf16x8*)&tile[((row0 + ir) * TH + cbase) * 32 + slot];
#pragma unroll
                for (int ky = 0; ky < KS; ++ky) {
                    const int mt = ir - ky;
                    if (mt < 0 || mt > 3) continue;
#pragma unroll
                    for (int nt = 0; nt < NTU; ++nt)
                        acc[mt][nt] = __builtin_amdgcn_mfma_f32_16x16x32_bf16(afr, B[ky][nt], acc[mt][nt], 0, 0, 0);
                }
            }
        }
        __syncthreads();   // protect tile from next slice's staging
    }

#pragma unroll
    for (int nt = 0; nt < NTU; ++nt) {
        const int co = (ntb + nt) * 16 + m;
        const float bv = (co < NSTORE) ? bias[co] : 0.f;
#pragma unroll
        for (int mt = 0; mt < 4; ++mt) {
            const int oy = ty0 + wv * 4 + mt;
#pragma unroll
            for (int j = 0; j < 4; ++j) {
                const int ox = tx0 + q * 4 + j;
                if (oy < Hout && ox < Wout && co < NSTORE) {
                    float v = acc[mt][nt][j] + bv;
                    if (RELU) v = fmaxf(v, 0.f);
                    size_t o = (((size_t)n * Hout + oy) * Wout + ox) * NSTORE + co;
                    if (OUTF32) ((float*)outv)[o] = v;
                    else ((unsigned short*)outv)[o] = f2bf(v);
                }
            }
        }
    }
}

// ---------------- dc1 assemble ----------------
__global__ __launch_bounds__(256) void dc1_assemble(
    const float* __restrict__ P, const float* __restrict__ S,
    const float* __restrict__ bias, int n0,
    unsigned short* __restrict__ out)
{
    const int gid = blockIdx.x * 256 + threadIdx.x;
    const int nl = gid / 4624;
    const int pix = gid % 4624;
    const int oy = pix / 68, ox = pix % 68;
    const int rc = (oy == 0) ? 0 : ((oy == 67) ? 2 : 1);
    const int cc = (ox == 0) ? 0 : ((ox == 67) ? 2 : 1);
    const float* Sp = S + ((size_t)(n0 + nl) * 9 + (rc * 3 + cc)) * 32;
    const float* Pp = P + (size_t)pix * 32;
    unsigned short v[32];
#pragma unroll
    for (int co = 0; co < 32; ++co)
        v[co] = f2bf(fmaxf(bias[co] + Pp[co] + Sp[co], 0.f));
    uint4* ob = (uint4*)(out + ((size_t)nl * 4624 + pix) * 32);
#pragma unroll
    for (int i = 0; i < 4; ++i) ob[i] = ((uint4*)v)[i];
}

// ---------------- encoder conv1 ----------------
__global__ __launch_bounds__(256) void conv_ec1(
    const float* __restrict__ in, const float* __restrict__ wts,
    const float* __restrict__ bias, unsigned short* __restrict__ out)
{
    __shared__ float tile[3][20][21];
    const int blk = blockIdx.x;
    const int n = blk >> 6;
    const int sub = blk & 63;
    const int t = sub >> 2;
    const int cog = sub & 3;
    const int ty0 = (t >> 2) * 16, tx0 = (t & 3) * 16;
    const int tid = threadIdx.x;
    for (int idx = tid; idx < 1200; idx += 256) {
        int ci = idx / 400, rc = idx % 400;
        int r = rc / 20, c = rc % 20;
        int gy = ty0 + r - 2, gx = tx0 + c - 2;
        float v = 0.f;
        if (gy >= 0 && gy < 64 && gx >= 0 && gx < 64)
            v = in[((size_t)n * 3 + ci) * 4096 + gy * 64 + gx];
        tile[ci][r][c] = v;
    }
    __syncthreads();
    const int lx = tid & 15, ly = tid >> 4;
    float acc[16];
#pragma unroll
    for (int co = 0; co < 16; ++co) acc[co] = bias[cog * 16 + co];
    for (int ci = 0; ci < 3; ++ci) {
        float val[25];
#pragma unroll
        for (int ky = 0; ky < 5; ++ky)
#pragma unroll
            for (int kx = 0; kx < 5; ++kx) val[ky * 5 + kx] = tile[ci][ly + ky][lx + kx];
#pragma unroll
        for (int co = 0; co < 16; ++co) {
            const float* wc = wts + (size_t)((cog * 16 + co) * 3 + ci) * 25;
            float a = acc[co];
#pragma unroll
            for (int tt = 0; tt < 25; ++tt) a = fmaf(val[tt], wc[tt], a);
            acc[co] = a;
        }
    }
    unsigned short tmp[16];
#pragma unroll
    for (int co = 0; co < 16; ++co) tmp[co] = f2bf(fmaxf(acc[co], 0.f));
    uint4* ob = (uint4*)(out + (((size_t)n * 64 + ty0 + ly) * 64 + tx0 + lx) * 64 + cog * 16);
    ob[0] = ((uint4*)tmp)[0];
    ob[1] = ((uint4*)tmp)[1];
}

// ---------------- encoder tail, MFMA (k/v out in bf16) ----------------
__global__ __launch_bounds__(256) void encoder_tail_mfma(
    const unsigned short* __restrict__ h4,
    const float* __restrict__ epw, const float* __restrict__ epb,
    const float* __restrict__ ln1g, const float* __restrict__ ln1b,
    const unsigned short* __restrict__ pfc1, const float* __restrict__ fc1b,
    const unsigned short* __restrict__ pfc2, const float* __restrict__ fc2b,
    const unsigned short* __restrict__ pkw, const unsigned short* __restrict__ pvw,
    unsigned short* __restrict__ kout, unsigned short* __restrict__ vout)
{
    __shared__ __align__(16) unsigned short X[64][72];
    const int b = blockIdx.x >> 6;
    const int y = blockIdx.x & 63;
    const int tid = threadIdx.x;

    {
        const int p = tid >> 2, sub = tid & 3;
        const unsigned short* hp = h4 + ((((size_t)b * 64 + y) * 64 + p) * 64) + sub * 16;
        unsigned short raw[16];
        *(uint4*)(raw)     = *(const uint4*)hp;
        *(uint4*)(raw + 8) = *(const uint4*)(hp + 8);
        const float fy = y * (1.f / 63.f), fx = p * (1.f / 63.f);
        float f[16];
        float s1 = 0.f, s2 = 0.f;
#pragma unroll
        for (int j = 0; j < 16; ++j) {
            int ch = sub * 16 + j;
            float pe = (1.f - fy) * epw[ch] + fy * epw[64 + ch]
                     + fx * epw[128 + ch] + (1.f - fx) * epw[192 + ch] + epb[ch];
            float v = bf2f(raw[j]) + pe;
            f[j] = v;
            s1 += v;
            s2 += v * v;
        }
        s1 += __shfl_xor(s1, 1, 64); s1 += __shfl_xor(s1, 2, 64);
        s2 += __shfl_xor(s2, 1, 64); s2 += __shfl_xor(s2, 2, 64);
        const float m = s1 * (1.f / 64.f);
        const float var = s2 * (1.f / 64.f) - m * m;
        const float inv = rsqrtf(var + 1e-5f);
        unsigned short xb[16];
#pragma unroll
        for (int j = 0; j < 16; ++j) {
            int ch = sub * 16 + j;
            xb[j] = f2bf((f[j] - m) * inv * ln1g[ch] + ln1b[ch]);
        }
        *(uint4*)&X[p][sub * 16]     = ((uint4*)xb)[0];
        *(uint4*)&X[p][sub * 16 + 8] = ((uint4*)xb)[1];
    }
    __syncthreads();

    const int w = tid >> 6, lane = tid & 63;
    const int q = lane >> 4, m_ = lane & 15;
    const int row0 = w * 16;

    {
        f32x4 a1[4];
#pragma unroll
        for (int nt = 0; nt < 4; ++nt) a1[nt] = (f32x4){0.f, 0.f, 0.f, 0.f};
#pragma unroll
        for (int ck = 0; ck < 2; ++ck) {
            bf16x8 afr = *(const bf16x8*)&X[row0 + m_][ck * 32 + q * 8];
#pragma unroll
            for (int nt = 0; nt < 4; ++nt) {
                bf16x8 bfr = *(const bf16x8*)(pfc1 + ((size_t)((ck * 4 + nt) * 64 + lane)) * 8);
                a1[nt] = __builtin_amdgcn_mfma_f32_16x16x32_bf16(afr, bfr, a1[nt], 0, 0, 0);
            }
        }
        __syncthreads();
#pragma unroll
        for (int nt = 0; nt < 4; ++nt) {
            const float bb = fc1b[nt * 16 + m_];
#pragma unroll
            for (int reg = 0; reg < 4; ++reg)
                X[row0 + q * 4 + reg][nt * 16 + m_] = f2bf(fmaxf(a1[nt][reg] + bb, 0.f));
        }
    }
    __syncthreads();

    {
        f32x4 a2[4];
#pragma unroll
        for (int nt = 0; nt < 4; ++nt) a2[nt] = (f32x4){0.f, 0.f, 0.f, 0.f};
#pragma unroll
        for (int ck = 0; ck < 2; ++ck) {
            bf16x8 afr = *(const bf16x8*)&X[row0 + m_][ck * 32 + q * 8];
#pragma unroll
            for (int nt = 0; nt < 4; ++nt) {
                bf16x8 bfr = *(const bf16x8*)(pfc2 + ((size_t)((ck * 4 + nt) * 64 + lane)) * 8);
                a2[nt] = __builtin_amdgcn_mfma_f32_16x16x32_bf16(afr, bfr, a2[nt], 0, 0, 0);
            }
        }
        __syncthreads();
#pragma unroll
        for (int nt = 0; nt < 4; ++nt) {
            const float bb = fc2b[nt * 16 + m_];
#pragma unroll
            for (int reg = 0; reg < 4; ++reg)
                X[row0 + q * 4 + reg][nt * 16 + m_] = f2bf(a2[nt][reg] + bb);
        }
    }
    __syncthreads();

    {
        f32x4 ak[4], av[4];
#pragma unroll
        for (int nt = 0; nt < 4; ++nt) {
            ak[nt] = (f32x4){0.f, 0.f, 0.f, 0.f};
            av[nt] = (f32x4){0.f, 0.f, 0.f, 0.f};
        }
#pragma unroll
        for (int ck = 0; ck < 2; ++ck) {
            bf16x8 afr = *(const bf16x8*)&X[row0 + m_][ck * 32 + q * 8];
#pragma unroll
            for (int nt = 0; nt < 4; ++nt) {
                bf16x8 bk = *(const bf16x8*)(pkw + ((size_t)((ck * 4 + nt) * 64 + lane)) * 8);
                bf16x8 bv = *(const bf16x8*)(pvw + ((size_t)((ck * 4 + nt) * 64 + lane)) * 8);
                ak[nt] = __builtin_amdgcn_mfma_f32_16x16x32_bf16(afr, bk, ak[nt], 0, 0, 0);
                av[nt] = __builtin_amdgcn_mfma_f32_16x16x32_bf16(afr, bv, av[nt], 0, 0, 0);
            }
        }
        const size_t base = ((size_t)b * 4096) + y * 64 + row0;
#pragma unroll
        for (int nt = 0; nt < 4; ++nt) {
            const int ch = nt * 16 + m_;
#pragma unroll
            for (int reg = 0; reg < 4; ++reg) {
                const size_t o = (base + q * 4 + reg) * 64 + ch;
                kout[o] = f2bf(ak[nt][reg]);
                vout[o] = f2bf(av[nt][reg]);
            }
        }
    }
}

// ---------------- slot init (+ rowsum zero) ----------------
__global__ __launch_bounds__(256) void slot_init(
    const float* __restrict__ noise, const float* __restrict__ init_slots,
    float* __restrict__ slots, float* __restrict__ rowsum)
{
    int i = blockIdx.x * 256 + threadIdx.x;
    if (i < 224) rowsum[i] = 0.f;
    if (i < 224 * 64) {
        int z = i & 63;
        float spl = log1pf(expf(init_slots[64 + z]));
        slots[i] = init_slots[z] + spl * noise[i];
    }
}

// ---------------- fused attention ----------------
__global__ __launch_bounds__(256) void attn_fused(
    const unsigned short* __restrict__ kbuf, const unsigned short* __restrict__ vbuf,
    const float* __restrict__ slots,
    const float* __restrict__ lnsg, const float* __restrict__ lnsb,
    const float* __restrict__ qw,
    float* __restrict__ part, float* __restrict__ rowsum)
{
    __shared__ float qs[7][64];
    __shared__ float ash[256][7];
    __shared__ float red7[7][4];
    __shared__ float redv[4][7][64];
    const int b = blockIdx.x >> 4;
    const int js = blockIdx.x & 15;
    const int j0 = js * 256;
    const int tid = threadIdx.x;
    const int lane = tid & 63, wv = tid >> 6;

    for (int i = wv; i < 7; i += 4) {
        float s = slots[(b * 7 + i) * 64 + lane];
        float m = wave_sum(s) * (1.f / 64.f);
        float d = s - m;
        float var = wave_sum(d * d) * (1.f / 64.f);
        float x = d * rsqrtf(var + 1e-5f) * lnsg[lane] + lnsb[lane];
        float qv = 0.f;
        for (int c = 0; c < 64; ++c) qv = fmaf(__shfl(x, c, 64), qw[c * 64 + lane], qv);
        qs[i][lane] = qv * SCALE_;
    }
    __syncthreads();

    {
        const int j = j0 + tid;
        float kr[64];
        const unsigned short* kp = kbuf + (((size_t)b * 4096) + j) * 64;
#pragma unroll
        for (int d8 = 0; d8 < 8; ++d8) {
            uint4 kv = ((const uint4*)kp)[d8];
            const unsigned short* h = (const unsigned short*)&kv;
#pragma unroll
            for (int z = 0; z < 8; ++z) kr[d8 * 8 + z] = bf2f(h[z]);
        }
        float dots[7];
#pragma unroll
        for (int i = 0; i < 7; ++i) {
            float a = 0.f;
#pragma unroll
            for (int d = 0; d < 64; ++d) a = fmaf(kr[d], qs[i][d], a);
            dots[i] = a;
        }
        float mx = dots[0];
#pragma unroll
        for (int i = 1; i < 7; ++i) mx = fmaxf(mx, dots[i]);
        float sum = 0.f;
#pragma unroll
        for (int i = 0; i < 7; ++i) { dots[i] = expf(dots[i] - mx); sum += dots[i]; }
        const float inv = 1.f / sum;
#pragma unroll
        for (int i = 0; i < 7; ++i) {
            float a = dots[i] * inv + 1e-8f;
            dots[i] = a;
            ash[tid][i] = a;
        }
#pragma unroll
        for (int i = 0; i < 7; ++i) {
            float s = wave_sum(dots[i]);
            if (lane == 0) red7[i][wv] = s;
        }
    }
    __syncthreads();
    if (tid < 7)
        atomicAdd(&rowsum[b * 7 + tid], red7[tid][0] + red7[tid][1] + red7[tid][2] + red7[tid][3]);

    {
        const int d = lane, jc = wv;
        float acc[7];
#pragma unroll
        for (int i = 0; i < 7; ++i) acc[i] = 0.f;
        for (int jl = jc; jl < 256; jl += 4) {
            float av = bf2f(vbuf[(((size_t)b * 4096) + j0 + jl) * 64 + d]);
#pragma unroll
            for (int i = 0; i < 7; ++i)
                acc[i] = fmaf(ash[jl][i], av, acc[i]);
        }
#pragma unroll
        for (int i = 0; i < 7; ++i) redv[jc][i][d] = acc[i];
    }
    __syncthreads();
    if (tid < 7 * 64) {
        int i = tid / 64, dd = tid % 64;
        float s = redv[0][i][dd] + redv[1][i][dd] + redv[2][i][dd] + redv[3][i][dd];
        part[((((size_t)b * 16) + js) * 7 + i) * 64 + dd] = s;
    }
}

// ---------------- GRU + residual MLP ----------------
__global__ __launch_bounds__(64) void gru_mlp(
    float* __restrict__ slots, const float* __restrict__ part,
    float* __restrict__ rowsum,
    const float* __restrict__ wih, const float* __restrict__ whh,
    const float* __restrict__ bih, const float* __restrict__ bhh,
    const float* __restrict__ lnfg, const float* __restrict__ lnfb,
    const float* __restrict__ m1w, const float* __restrict__ m1b,
    const float* __restrict__ m2w, const float* __restrict__ m2b)
{
    const int n = blockIdx.x;
    const int b = n / 7, i = n % 7;
    const int l = threadIdx.x;
    float upd = 0.f;
    for (int js = 0; js < 16; ++js)
        upd += part[((((size_t)b * 16) + js) * 7 + i) * 64 + l];
    upd /= rowsum[n];
    if (l == 0) rowsum[n] = 0.f;
    const float prev = slots[n * 64 + l];
    float gi0 = bih[l], gi1 = bih[64 + l], gi2 = bih[128 + l];
    float gh0 = bhh[l], gh1 = bhh[64 + l], gh2 = bhh[128 + l];
    for (int c = 0; c < 64; ++c) {
        float u = __shfl(upd, c, 64), p = __shfl(prev, c, 64);
        gi0 = fmaf(u, wih[l * 64 + c], gi0);
        gi1 = fmaf(u, wih[(64 + l) * 64 + c], gi1);
        gi2 = fmaf(u, wih[(128 + l) * 64 + c], gi2);
        gh0 = fmaf(p, whh[l * 64 + c], gh0);
        gh1 = fmaf(p, whh[(64 + l) * 64 + c], gh1);
        gh2 = fmaf(p, whh[(128 + l) * 64 + c], gh2);
    }
    float r  = 1.f / (1.f + expf(-(gi0 + gh0)));
    float zg = 1.f / (1.f + expf(-(gi1 + gh1)));
    float nn = tanhf(gi2 + r * gh2);
    float s = (1.f - zg) * nn + zg * prev;
    float m = wave_sum(s) * (1.f / 64.f);
    float d = s - m;
    float var = wave_sum(d * d) * (1.f / 64.f);
    float x = d * rsqrtf(var + 1e-5f) * lnfg[l] + lnfb[l];
    float h0 = m1b[l], h1 = m1b[64 + l];
    for (int c = 0; c < 64; ++c) {
        float xv = __shfl(x, c, 64);
        h0 = fmaf(xv, m1w[c * 128 + l], h0);
        h1 = fmaf(xv, m1w[c * 128 + 64 + l], h1);
    }
    h0 = fmaxf(h0, 0.f); h1 = fmaxf(h1, 0.f);
    float o = m2b[l];
    for (int c = 0; c < 64; ++c) {
        o = fmaf(__shfl(h0, c, 64), m2w[c * 64 + l], o);
        o = fmaf(__shfl(h1, c, 64), m2w[(64 + c) * 64 + l], o);
    }
    slots[n * 64 + l] = s + o;
}

// ---------------- finalize ----------------
__global__ __launch_bounds__(256) void finalize_k(
    const float* __restrict__ dc4out, const float* __restrict__ inputs,
    float* __restrict__ out)
{
    const int tid = threadIdx.x;
    const int gp = blockIdx.x * 256 + tid;
    const int b = gp >> 12, p = gp & 4095;
    float4 o4[7];
#pragma unroll
    for (int k = 0; k < 7; ++k)
        o4[k] = ((const float4*)dc4out)[(size_t)(b * 7 + k) * 4096 + p];
    float mx = o4[0].w;
#pragma unroll
    for (int k = 1; k < 7; ++k) mx = fmaxf(mx, o4[k].w);
    float s = 0.f;
#pragma unroll
    for (int k = 0; k < 7; ++k) s += expf(o4[k].w - mx);
    const float lse = mx + logf(s);
    float recon0 = 0.f, recon1 = 0.f, recon2 = 0.f;
    float* xl = out + 1;
    float* ml = out + 2752513;
#pragma unroll
    for (int k = 0; k < 7; ++k) {
        float lp = o4[k].w - lse;
        ml[((size_t)(b * 7 + k)) * 4096 + p] = lp;
        float w = expf(lp);
        float x0 = 1.f / (1.f + expf(-o4[k].x));
        float x1 = 1.f / (1.f + expf(-o4[k].y));
        float x2 = 1.f / (1.f + expf(-o4[k].z));
        xl[(((size_t)(b * 7 + k)) * 3 + 0) * 4096 + p] = x0;
        xl[(((size_t)(b * 7 + k)) * 3 + 1) * 4096 + p] = x1;
        xl[(((size_t)(b * 7 + k)) * 3 + 2) * 4096 + p] = x2;
        recon0 = fmaf(x0, w, recon0);
        recon1 = fmaf(x1, w, recon1);
        recon2 = fmaf(x2, w, recon2);
    }
    float err = 0.f;
    {
        float xo = (inputs[((size_t)b * 3 + 0) * 4096 + p] + 1.f) * 0.5f;
        float dd = xo - recon0; err += dd * dd;
        xo = (inputs[((size_t)b * 3 + 1) * 4096 + p] + 1.f) * 0.5f;
        dd = xo - recon1; err += dd * dd;
        xo = (inputs[((size_t)b * 3 + 2) * 4096 + p] + 1.f) * 0.5f;
        dd = xo - recon2; err += dd * dd;
    }
    float wsum = wave_sum(err);
    __shared__ float red[4];
    const int lane = tid & 63, wv = tid >> 6;
    if (lane == 0) red[wv] = wsum;
    __syncthreads();
    if (tid == 0) atomicAdd(out, (red[0] + red[1] + red[2] + red[3]) * (1.f / 32.f));
}

// ---------------- launch ----------------
extern "C" void kernel_launch(void* const* d_in, const int* in_sizes, int n_in,
                              void* d_out, int out_size, void* d_ws, size_t ws_size,
                              hipStream_t stream) {
    (void)in_sizes; (void)n_in; (void)out_size; (void)ws_size;
    const float* inputs = (const float*)d_in[0];
    const float* noise  = (const float*)d_in[1];
    const float* epw  = (const float*)d_in[2];
    const float* epb  = (const float*)d_in[3];
    const float* ec1w = (const float*)d_in[4];
    const float* ec1b = (const float*)d_in[5];
    const float* ec2w = (const float*)d_in[6];
    const float* ec2b = (const float*)d_in[7];
    const float* ec3w = (const float*)d_in[8];
    const float* ec3b = (const float*)d_in[9];
    const float* ec4w = (const float*)d_in[10];
    const float* ec4b = (const float*)d_in[11];
    const float* ln1g = (const float*)d_in[12];
    const float* ln1b = (const float*)d_in[13];
    const float* fc1w = (const float*)d_in[14];
    const float* fc1b = (const float*)d_in[15];
    const float* fc2w = (const float*)d_in[16];
    const float* fc2b = (const float*)d_in[17];
    const float* lnsg = (const float*)d_in[18];
    const float* lnsb = (const float*)d_in[19];
    const float* lnfg = (const float*)d_in[20];
    const float* lnfb = (const float*)d_in[21];
    const float* qw   = (const float*)d_in[22];
    const float* kw   = (const float*)d_in[23];
    const float* vw   = (const float*)d_in[24];
    const float* m1w  = (const float*)d_in[25];
    const float* m1b  = (const float*)d_in[26];
    const float* m2w  = (const float*)d_in[27];
    const float* m2b  = (const float*)d_in[28];
    const float* wih  = (const float*)d_in[29];
    const float* whh  = (const float*)d_in[30];
    const float* bih  = (const float*)d_in[31];
    const float* bhh  = (const float*)d_in[32];
    const float* init_slots = (const float*)d_in[33];
    const float* dpw  = (const float*)d_in[34];
    const float* dpb  = (const float*)d_in[35];
    const float* dc1w = (const float*)d_in[36];
    const float* dc1b = (const float*)d_in[37];
    const float* dc2w = (const float*)d_in[38];
    const float* dc2b = (const float*)d_in[39];
    const float* dc3w = (const float*)d_in[40];
    const float* dc3b = (const float*)d_in[41];
    const float* dc4w = (const float*)d_in[42];
    const float* dc4b = (const float*)d_in[43];

    float* ws = (float*)d_ws;
    unsigned short* B0 = (unsigned short*)(ws + WS_B0);
    unsigned short* B1 = (unsigned short*)(ws + WS_B1);
    unsigned short* K = (unsigned short*)(ws + WS_K);
    unsigned short* V = (unsigned short*)(ws + WS_V);
    unsigned short* dping = (unsigned short*)(ws + WS_B0);
    unsigned short* dpong = (unsigned short*)(ws + WS_K);
    float* dc4out = ws + WS_V;
    unsigned short* PK = (unsigned short*)(ws + WS_V + 4194304u);
    unsigned short* p_ec2 = PK, *p_ec3 = PK + 102400, *p_ec4 = PK + 204800;
    unsigned short* p_dc1 = PK, *p_dc2 = PK + 51200, *p_dc3 = PK + 76800, *p_dc4 = PK + 102400;
    float* attn  = ws + WS_ATTN;
    unsigned short* PFC = (unsigned short*)attn;
    unsigned short* p_fc1 = PFC;
    unsigned short* peb = (unsigned short*)(attn + OFF_PEB);
    float* wclsb = attn + OFF_WCLS;
    float* Sbuf  = attn + OFF_S;
    float* zbias = attn + OFF_ZB;
    float* part  = ws + WS_PART;
    float* P     = ws + WS_PART;
    float* zpage = ws + WS_ZP;
    float* slots = ws + WS_SLOT;
    float* rowsum = ws + WS_ROW;
    float* out = (float*)d_out;
    const unsigned short* zp16 = (const unsigned short*)zpage;

    // ---- pack encoder weights + fc mats + zero page (1 launch) ----
    pack_enc<<<159, 256, 0, stream>>>(ec2w, ec3w, ec4w, p_ec2,
                                      fc1w, fc2w, kw, vw, p_fc1, zpage);

    // ---- encoder ----
    conv_ec1<<<2048, 256, 0, stream>>>(inputs, ec1w, ec1b, B0);
    conv_mfma<64, 4, 2, 5, 2, 64, 1, 0><<<1024, 256, 0, stream>>>(B0, p_ec2, ec2b, B1, zp16, 64, 64, 64, 64, 4, 4);
    conv_mfma<64, 4, 2, 5, 2, 64, 1, 0><<<1024, 256, 0, stream>>>(B1, p_ec3, ec3b, B0, zp16, 64, 64, 64, 64, 4, 4);
    conv_mfma<64, 4, 2, 5, 2, 64, 1, 0><<<1024, 256, 0, stream>>>(B0, p_ec4, ec4b, B1, zp16, 64, 64, 64, 64, 4, 4);
    encoder_tail_mfma<<<2048, 256, 0, stream>>>(B1, epw, epb, ln1g, ln1b,
                                                p_fc1, fc1b, p_fc1 + 4096, fc2b,
                                                p_fc1 + 8192, p_fc1 + 12288, K, V);
    slot_init<<<56, 256, 0, stream>>>(noise, init_slots, slots, rowsum);

    // ---- 3 slot-attention iterations ----
    for (int it = 0; it < 3; ++it) {
        attn_fused<<<512, 256, 0, stream>>>(K, V, slots, lnsg, lnsb, qw, part, rowsum);
        gru_mlp<<<224, 64, 0, stream>>>(slots, part, rowsum, wih, whh, bih, bhh,
                                        lnfg, lnfb, m1w, m1b, m2w, m2b);
    }

    // ---- decoder prep (1 launch) + Wcls/S (2 tiny launches) ----
    dec_prep<<<128, 256, 0, stream>>>(dc1w, dc2w, dc3w, dc4w,
                                      p_dc1, p_dc2, p_dc3, p_dc4,
                                      dpw, dpb, peb, zbias, slots, out);
    wcls_build<<<72, 256, 0, stream>>>(dc1w, wclsb);
    slot_s<<<252, 256, 0, stream>>>(slots, wclsb, Sbuf);
    conv_mfma<64, 2, 2, 5, 1, 32, 0, 1><<<25, 256, 0, stream>>>(peb, p_dc1, zbias, P, zp16, 70, 70, 68, 68, 5, 5);

    // ---- decoder, 2 chunks of 112 images ----
    for (int ch = 0; ch < 2; ++ch) {
        float* d4o = dc4out + (size_t)ch * 112 * 4 * 4096;
        dc1_assemble<<<2023, 256, 0, stream>>>(P, Sbuf, dc1b, ch * 112, dping);
        conv_mfma<32, 2, 2, 5, 1, 32, 1, 0><<<2800, 256, 0, stream>>>(dping, p_dc2, dc2b, dpong, zp16, 68, 68, 66, 66, 5, 5);
        conv_mfma<32, 2, 2, 5, 1, 32, 1, 0><<<1792, 256, 0, stream>>>(dpong, p_dc3, dc3b, dping, zp16, 66, 66, 64, 64, 4, 4);
        conv_mfma<32, 1, 1, 3, 1, 4, 0, 1><<<1792, 256, 0, stream>>>(dping, p_dc4, dc4b, d4o, zp16, 64, 64, 64, 64, 4, 4);
    }

    // ---- outputs ----
    finalize_k<<<512, 256, 0, stream>>>(dc4out, inputs, out);
}

// Round 13
// 716.373 us; speedup vs baseline: 1.0019x; 1.0019x over previous
//
#include <hip/hip_runtime.h>
#include <math.h>

typedef short bf16x8 __attribute__((ext_vector_type(8)));
typedef float f32x4 __attribute__((ext_vector_type(4)));

// workspace layout (float offsets)
#define WS_B0   0u
#define WS_B1   4194304u
#define WS_K    8388608u
#define WS_V    16777216u
#define WS_ATTN 25165824u
#define WS_PART 26083328u
#define WS_ZP   26312704u
#define WS_SLOT 26327040u
#define WS_ROW  26341376u
#define SCALE_ 0.125f

#define OFF_PEB   0u
#define OFF_WCLS  160000u
#define OFF_S     180000u
#define OFF_ZB    250000u

__device__ __forceinline__ float wave_sum(float v) {
#pragma unroll
    for (int m = 32; m >= 1; m >>= 1) v += __shfl_xor(v, m, 64);
    return v;
}
__device__ __forceinline__ unsigned short f2bf(float f) {
    unsigned u = __float_as_uint(f);
    u = u + 0x7fffu + ((u >> 16) & 1u);
    return (unsigned short)(u >> 16);
}
__device__ __forceinline__ float bf2f(unsigned short h) {
    return __uint_as_float(((unsigned)h) << 16);
}
__device__ __forceinline__ void gl_lds16(const void* src, void* lds_base) {
    __builtin_amdgcn_global_load_lds(
        (const __attribute__((address_space(1))) unsigned int*)src,
        (__attribute__((address_space(3))) unsigned int*)lds_base,
        16, 0, 0);
}

// ---------------- weight packing (device helper, B-fragment order) ----------------
__device__ __forceinline__ void pack_one(
    const float* __restrict__ w, unsigned short* __restrict__ wp,
    int CIN, int COUT_STORE, int KS, int NT, int t)
{
    int lane = t & 63;
    int nt = (t >> 6) % NT;
    int ch = t / (64 * NT);
    int CPT = CIN / 32;
    int cic = ch % CPT;
    int tap = ch / CPT;
    int ky = tap / KS, kx = tap % KS;
    int co = nt * 16 + (lane & 15);
    int k0 = cic * 32 + (lane >> 4) * 8;
    unsigned short v[8];
#pragma unroll
    for (int j = 0; j < 8; ++j) {
        int ci = k0 + j;
        float f = (co < COUT_STORE) ? w[((size_t)(co * CIN + ci) * KS + ky) * KS + kx] : 0.f;
        v[j] = f2bf(f);
    }
    *(uint4*)(wp + (size_t)t * 8) = *(uint4*)v;
}

// ---------------- encoder-side packing: 3 convs + 4 fc mats + zero page ----------------
__global__ __launch_bounds__(256) void pack_enc(
    const float* __restrict__ ec2w, const float* __restrict__ ec3w,
    const float* __restrict__ ec4w, unsigned short* __restrict__ wp,
    const float* __restrict__ fc1w, const float* __restrict__ fc2w,
    const float* __restrict__ kw, const float* __restrict__ vw,
    unsigned short* __restrict__ pfc, float* __restrict__ zpage)
{
    if (blockIdx.x == 0 && threadIdx.x < 64) zpage[threadIdx.x] = 0.f;
    int t = blockIdx.x * 256 + threadIdx.x;
    if (t < 38400) {
        int which = t / 12800;
        int tt = t % 12800;
        const float* w = (which == 0) ? ec2w : ((which == 1) ? ec3w : ec4w);
        pack_one(w, wp + (size_t)which * 102400, 64, 64, 5, 4, tt);
        return;
    }
    t -= 38400;
    if (t < 2048) {
        int which = t / 512;
        int tt = t % 512;
        const float* w = (which == 0) ? fc1w : ((which == 1) ? fc2w : ((which == 2) ? kw : vw));
        unsigned short* dst = pfc + (size_t)which * 4096;
        int lane = tt & 63;
        int nt = (tt >> 6) & 3;
        int ck = tt >> 8;
        int n = nt * 16 + (lane & 15);
        int k0 = ck * 32 + (lane >> 4) * 8;
        unsigned short v[8];
#pragma unroll
        for (int j = 0; j < 8; ++j) v[j] = f2bf(w[(size_t)(k0 + j) * 64 + n]);
        *(uint4*)(dst + (size_t)tt * 8) = *(uint4*)v;
    }
}

// ---------------- decoder prep: packs + pe field + slot copy + zeroes ----------------
__global__ __launch_bounds__(256) void dec_prep(
    const float* __restrict__ dc1w, const float* __restrict__ dc2w,
    const float* __restrict__ dc3w, const float* __restrict__ dc4w,
    unsigned short* __restrict__ p_dc1, unsigned short* __restrict__ p_dc2,
    unsigned short* __restrict__ p_dc3, unsigned short* __restrict__ p_dc4,
    const float* __restrict__ dpw, const float* __restrict__ dpb,
    unsigned short* __restrict__ peb, float* __restrict__ zbias,
    const float* __restrict__ slots, float* __restrict__ out)
{
    int t = blockIdx.x * 256 + threadIdx.x;
    if (t < 6400) { pack_one(dc1w, p_dc1, 64, 32, 5, 2, t); return; }
    t -= 6400;
    if (t < 3200) { pack_one(dc2w, p_dc2, 32, 32, 5, 2, t); return; }
    t -= 3200;
    if (t < 3200) { pack_one(dc3w, p_dc3, 32, 32, 5, 2, t); return; }
    t -= 3200;
    if (t < 576)  { pack_one(dc4w, p_dc4, 32, 4, 3, 1, t); return; }
    t -= 576;
    if (t < 4900) {
        const int iy = t / 70, ix = t % 70;
        const float fy = iy * (1.f / 69.f), fx = ix * (1.f / 69.f);
        unsigned short v[64];
#pragma unroll
        for (int ci = 0; ci < 64; ++ci) {
            float p = (1.f - fy) * dpw[ci] + fy * dpw[64 + ci]
                    + fx * dpw[128 + ci] + (1.f - fx) * dpw[192 + ci] + dpb[ci];
            v[ci] = f2bf(p);
        }
        uint4* ob = (uint4*)(peb + (size_t)t * 64);
#pragma unroll
        for (int i = 0; i < 8; ++i) ob[i] = ((uint4*)v)[i];
        return;
    }
    t -= 4900;
    if (t < 14336) { out[3670017 + t] = slots[t]; return; }
    t -= 14336;
    if (t < 32) zbias[t] = 0.f;
    else if (t == 32) out[0] = 0.f;
}

// ---------------- Wcls[9][32][64] ----------------
__global__ __launch_bounds__(256) void wcls_build(
    const float* __restrict__ w, float* __restrict__ wcls)
{
    int idx = blockIdx.x * 256 + threadIdx.x;
    if (idx >= 9 * 32 * 64) return;
    int cls = idx / (32 * 64);
    int co = (idx / 64) % 32;
    int ci = idx % 64;
    int rc = cls / 3, cc = cls % 3;
    int ky0 = (rc == 0) ? 1 : 0, ky1 = (rc == 2) ? 3 : 4;
    int kx0 = (cc == 0) ? 1 : 0, kx1 = (cc == 2) ? 3 : 4;
    float s = 0.f;
    const float* wb = w + (size_t)(co * 64 + ci) * 25;
    for (int ky = ky0; ky <= ky1; ++ky)
        for (int kx = kx0; kx <= kx1; ++kx)
            s += wb[ky * 5 + kx];
    wcls[idx] = s;
}

// ---------------- S[224][9][32] = slots @ Wcls^T ----------------
__global__ __launch_bounds__(256) void slot_s(
    const float* __restrict__ slots, const float* __restrict__ wcls,
    float* __restrict__ S)
{
    int idx = blockIdx.x * 256 + threadIdx.x;
    if (idx >= 224 * 9 * 32) return;
    int n = idx / (9 * 32);
    int cls = (idx / 32) % 9;
    int co = idx % 32;
    const float* sl = slots + n * 64;
    const float* wc = wcls + (size_t)(cls * 32 + co) * 64;
    float s = 0.f;
#pragma unroll
    for (int ci = 0; ci < 64; ++ci) s = fmaf(sl[ci], wc[ci], s);
    S[idx] = s;
}

// ---------------- MFMA implicit-GEMM conv, per-K-slice DMA-staged LDS ----------------
// Tile holds ONE 32-channel K-slice (TH*TH*32 bf16 = 25.6KB max).
// Chunk swizzle pi(c,g) = (g + (c>>1)) & 3: spreads b128 reads over all 8
// bank-quads (2 lanes each = conflict-free) despite the 64B pixel stride.
template<int CIN, int NTT, int NTU, int KS, int PAD, int NSTORE, int RELU, int OUTF32>
__global__ __launch_bounds__(256) void conv_mfma(
    const unsigned short* __restrict__ in, const unsigned short* __restrict__ wpack,
    const float* __restrict__ bias, void* __restrict__ outv,
    const unsigned short* __restrict__ zpage,
    int Hin, int Win, int Hout, int Wout, int tilesX, int tilesY)
{
    constexpr int TS = 16, TH = TS + KS - 1;
    constexpr int CPT = CIN / 32;
    constexpr int CS = NTT / NTU;
    constexpr int TOTCH = TH * TH * 4;                 // chunks per 32-ch slice
    __shared__ __align__(16) unsigned short tile[TOTCH * 8];
    const int tpb = tilesX * tilesY;
    const int blk = blockIdx.x;
    const int n = blk / (tpb * CS);
    const int rem = blk % (tpb * CS);
    const int t = rem / CS;
    const int cog = rem % CS;
    const int ntb = cog * NTU;
    const int ty0 = (t / tilesX) * TS, tx0 = (t % tilesX) * TS;
    const int tid = threadIdx.x;
    const int wv = tid >> 6, lane = tid & 63;
    const int q = lane >> 4, m = lane & 15;
    const int row0 = wv * 4;

    const unsigned short* inb = in + (size_t)n * Hin * Win * CIN;

    f32x4 acc[4][NTU];
#pragma unroll
    for (int mt = 0; mt < 4; ++mt)
#pragma unroll
        for (int nt = 0; nt < NTU; ++nt) acc[mt][nt] = (f32x4){0.f, 0.f, 0.f, 0.f};

#pragma unroll
    for (int cic = 0; cic < CPT; ++cic) {
        // ---- stage this 32-channel slice via global_load_lds ----
        for (int cb = wv * 64; cb < TOTCH; cb += 256) {
            const int idx = cb + lane;
            const int r = idx / (TH * 4);
            const int p = idx % (TH * 4);
            const int c = p / 4;
            const int chunk = p & 3;
            const int g = (chunk - (c >> 1)) & 3;       // pi(c,g)=(g+(c>>1))&3
            const int iy = ty0 - PAD + r, ix = tx0 - PAD + c;
            const bool ok = (idx < TOTCH) && ((unsigned)iy < (unsigned)Hin) && ((unsigned)ix < (unsigned)Win);
            const unsigned short* src = ok ?
                (inb + ((size_t)iy * Win + ix) * CIN + cic * 32 + g * 8) : zpage;
            gl_lds16(src, tile + (size_t)cb * 8);
        }
        __syncthreads();

#pragma unroll
        for (int kx = 0; kx < KS; ++kx) {
            bf16x8 B[KS][NTU];
#pragma unroll
            for (int ky = 0; ky < KS; ++ky)
#pragma unroll
                for (int nt = 0; nt < NTU; ++nt)
                    B[ky][nt] = *(const bf16x8*)(wpack +
                        ((size_t)(((ky * KS + kx) * CPT + cic) * NTT + ntb + nt) * 64 + lane) * 8);
            const int cbase = m + kx;
            const int slot = ((q + (cbase >> 1)) & 3) * 8;
#pragma unroll
            for (int ir = 0; ir < KS + 3; ++ir) {
                bf16x8 afr = *(const bf16x8*)&tile[((row0 + ir) * TH + cbase) * 32 + slot];
#pragma unroll
                for (int ky = 0; ky < KS; ++ky) {
                    const int mt = ir - ky;
                    if (mt < 0 || mt > 3) continue;
#pragma unroll
                    for (int nt = 0; nt < NTU; ++nt)
                        acc[mt][nt] = __builtin_amdgcn_mfma_f32_16x16x32_bf16(afr, B[ky][nt], acc[mt][nt], 0, 0, 0);
                }
            }
        }
        __syncthreads();   // protect tile from next slice's staging
    }

#pragma unroll
    for (int nt = 0; nt < NTU; ++nt) {
        const int co = (ntb + nt) * 16 + m;
        const float bv = (co < NSTORE) ? bias[co] : 0.f;
#pragma unroll
        for (int mt = 0; mt < 4; ++mt) {
            const int oy = ty0 + wv * 4 + mt;
#pragma unroll
            for (int j = 0; j < 4; ++j) {
                const int ox = tx0 + q * 4 + j;
                if (oy < Hout && ox < Wout && co < NSTORE) {
                    float v = acc[mt][nt][j] + bv;
                    if (RELU) v = fmaxf(v, 0.f);
                    size_t o = (((size_t)n * Hout + oy) * Wout + ox) * NSTORE + co;
                    if (OUTF32) ((float*)outv)[o] = v;
                    else ((unsigned short*)outv)[o] = f2bf(v);
                }
            }
        }
    }
}

// ---------------- dc1 assemble ----------------
__global__ __launch_bounds__(256) void dc1_assemble(
    const float* __restrict__ P, const float* __restrict__ S,
    const float* __restrict__ bias, int n0,
    unsigned short* __restrict__ out)
{
    const int gid = blockIdx.x * 256 + threadIdx.x;
    const int nl = gid / 4624;
    const int pix = gid % 4624;
    const int oy = pix / 68, ox = pix % 68;
    const int rc = (oy == 0) ? 0 : ((oy == 67) ? 2 : 1);
    const int cc = (ox == 0) ? 0 : ((ox == 67) ? 2 : 1);
    const float* Sp = S + ((size_t)(n0 + nl) * 9 + (rc * 3 + cc)) * 32;
    const float* Pp = P + (size_t)pix * 32;
    unsigned short v[32];
#pragma unroll
    for (int co = 0; co < 32; ++co)
        v[co] = f2bf(fmaxf(bias[co] + Pp[co] + Sp[co], 0.f));
    uint4* ob = (uint4*)(out + ((size_t)nl * 4624 + pix) * 32);
#pragma unroll
    for (int i = 0; i < 4; ++i) ob[i] = ((uint4*)v)[i];
}

// ---------------- encoder conv1 ----------------
__global__ __launch_bounds__(256) void conv_ec1(
    const float* __restrict__ in, const float* __restrict__ wts,
    const float* __restrict__ bias, unsigned short* __restrict__ out)
{
    __shared__ float tile[3][20][21];
    const int blk = blockIdx.x;
    const int n = blk >> 6;
    const int sub = blk & 63;
    const int t = sub >> 2;
    const int cog = sub & 3;
    const int ty0 = (t >> 2) * 16, tx0 = (t & 3) * 16;
    const int tid = threadIdx.x;
    for (int idx = tid; idx < 1200; idx += 256) {
        int ci = idx / 400, rc = idx % 400;
        int r = rc / 20, c = rc % 20;
        int gy = ty0 + r - 2, gx = tx0 + c - 2;
        float v = 0.f;
        if (gy >= 0 && gy < 64 && gx >= 0 && gx < 64)
            v = in[((size_t)n * 3 + ci) * 4096 + gy * 64 + gx];
        tile[ci][r][c] = v;
    }
    __syncthreads();
    const int lx = tid & 15, ly = tid >> 4;
    float acc[16];
#pragma unroll
    for (int co = 0; co < 16; ++co) acc[co] = bias[cog * 16 + co];
    for (int ci = 0; ci < 3; ++ci) {
        float val[25];
#pragma unroll
        for (int ky = 0; ky < 5; ++ky)
#pragma unroll
            for (int kx = 0; kx < 5; ++kx) val[ky * 5 + kx] = tile[ci][ly + ky][lx + kx];
#pragma unroll
        for (int co = 0; co < 16; ++co) {
            const float* wc = wts + (size_t)((cog * 16 + co) * 3 + ci) * 25;
            float a = acc[co];
#pragma unroll
            for (int tt = 0; tt < 25; ++tt) a = fmaf(val[tt], wc[tt], a);
            acc[co] = a;
        }
    }
    unsigned short tmp[16];
#pragma unroll
    for (int co = 0; co < 16; ++co) tmp[co] = f2bf(fmaxf(acc[co], 0.f));
    uint4* ob = (uint4*)(out + (((size_t)n * 64 + ty0 + ly) * 64 + tx0 + lx) * 64 + cog * 16);
    ob[0] = ((uint4*)tmp)[0];
    ob[1] = ((uint4*)tmp)[1];
}

// ---------------- encoder tail, MFMA (k/v out in bf16) ----------------
__global__ __launch_bounds__(256) void encoder_tail_mfma(
    const unsigned short* __restrict__ h4,
    const float* __restrict__ epw, const float* __restrict__ epb,
    const float* __restrict__ ln1g, const float* __restrict__ ln1b,
    const unsigned short* __restrict__ pfc1, const float* __restrict__ fc1b,
    const unsigned short* __restrict__ pfc2, const float* __restrict__ fc2b,
    const unsigned short* __restrict__ pkw, const unsigned short* __restrict__ pvw,
    unsigned short* __restrict__ kout, unsigned short* __restrict__ vout)
{
    __shared__ __align__(16) unsigned short X[64][72];
    const int b = blockIdx.x >> 6;
    const int y = blockIdx.x & 63;
    const int tid = threadIdx.x;

    {
        const int p = tid >> 2, sub = tid & 3;
        const unsigned short* hp = h4 + ((((size_t)b * 64 + y) * 64 + p) * 64) + sub * 16;
        unsigned short raw[16];
        *(uint4*)(raw)     = *(const uint4*)hp;
        *(uint4*)(raw + 8) = *(const uint4*)(hp + 8);
        const float fy = y * (1.f / 63.f), fx = p * (1.f / 63.f);
        float f[16];
        float s1 = 0.f, s2 = 0.f;
#pragma unroll
        for (int j = 0; j < 16; ++j) {
            int ch = sub * 16 + j;
            float pe = (1.f - fy) * epw[ch] + fy * epw[64 + ch]
                     + fx * epw[128 + ch] + (1.f - fx) * epw[192 + ch] + epb[ch];
            float v = bf2f(raw[j]) + pe;
            f[j] = v;
            s1 += v;
            s2 += v * v;
        }
        s1 += __shfl_xor(s1, 1, 64); s1 += __shfl_xor(s1, 2, 64);
        s2 += __shfl_xor(s2, 1, 64); s2 += __shfl_xor(s2, 2, 64);
        const float m = s1 * (1.f / 64.f);
        const float var = s2 * (1.f / 64.f) - m * m;
        const float inv = rsqrtf(var + 1e-5f);
        unsigned short xb[16];
#pragma unroll
        for (int j = 0; j < 16; ++j) {
            int ch = sub * 16 + j;
            xb[j] = f2bf((f[j] - m) * inv * ln1g[ch] + ln1b[ch]);
        }
        *(uint4*)&X[p][sub * 16]     = ((uint4*)xb)[0];
        *(uint4*)&X[p][sub * 16 + 8] = ((uint4*)xb)[1];
    }
    __syncthreads();

    const int w = tid >> 6, lane = tid & 63;
    const int q = lane >> 4, m_ = lane & 15;
    const int row0 = w * 16;

    {
        f32x4 a1[4];
#pragma unroll
        for (int nt = 0; nt < 4; ++nt) a1[nt] = (f32x4){0.f, 0.f, 0.f, 0.f};
#pragma unroll
        for (int ck = 0; ck < 2; ++ck) {
            bf16x8 afr = *(const bf16x8*)&X[row0 + m_][ck * 32 + q * 8];
#pragma unroll
            for (int nt = 0; nt < 4; ++nt) {
                bf16x8 bfr = *(const bf16x8*)(pfc1 + ((size_t)((ck * 4 + nt) * 64 + lane)) * 8);
                a1[nt] = __builtin_amdgcn_mfma_f32_16x16x32_bf16(afr, bfr, a1[nt], 0, 0, 0);
            }
        }
        __syncthreads();
#pragma unroll
        for (int nt = 0; nt < 4; ++nt) {
            const float bb = fc1b[nt * 16 + m_];
#pragma unroll
            for (int reg = 0; reg < 4; ++reg)
                X[row0 + q * 4 + reg][nt * 16 + m_] = f2bf(fmaxf(a1[nt][reg] + bb, 0.f));
        }
    }
    __syncthreads();

    {
        f32x4 a2[4];
#pragma unroll
        for (int nt = 0; nt < 4; ++nt) a2[nt] = (f32x4){0.f, 0.f, 0.f, 0.f};
#pragma unroll
        for (int ck = 0; ck < 2; ++ck) {
            bf16x8 afr = *(const bf16x8*)&X[row0 + m_][ck * 32 + q * 8];
#pragma unroll
            for (int nt = 0; nt < 4; ++nt) {
                bf16x8 bfr = *(const bf16x8*)(pfc2 + ((size_t)((ck * 4 + nt) * 64 + lane)) * 8);
                a2[nt] = __builtin_amdgcn_mfma_f32_16x16x32_bf16(afr, bfr, a2[nt], 0, 0, 0);
            }
        }
        __syncthreads();
#pragma unroll
        for (int nt = 0; nt < 4; ++nt) {
            const float bb = fc2b[nt * 16 + m_];
#pragma unroll
            for (int reg = 0; reg < 4; ++reg)
                X[row0 + q * 4 + reg][nt * 16 + m_] = f2bf(a2[nt][reg] + bb);
        }
    }
    __syncthreads();

    {
        f32x4 ak[4], av[4];
#pragma unroll
        for (int nt = 0; nt < 4; ++nt) {
            ak[nt] = (f32x4){0.f, 0.f, 0.f, 0.f};
            av[nt] = (f32x4){0.f, 0.f, 0.f, 0.f};
        }
#pragma unroll
        for (int ck = 0; ck < 2; ++ck) {
            bf16x8 afr = *(const bf16x8*)&X[row0 + m_][ck * 32 + q * 8];
#pragma unroll
            for (int nt = 0; nt < 4; ++nt) {
                bf16x8 bk = *(const bf16x8*)(pkw + ((size_t)((ck * 4 + nt) * 64 + lane)) * 8);
                bf16x8 bv = *(const bf16x8*)(pvw + ((size_t)((ck * 4 + nt) * 64 + lane)) * 8);
                ak[nt] = __builtin_amdgcn_mfma_f32_16x16x32_bf16(afr, bk, ak[nt], 0, 0, 0);
                av[nt] = __builtin_amdgcn_mfma_f32_16x16x32_bf16(afr, bv, av[nt], 0, 0, 0);
            }
        }
        const size_t base = ((size_t)b * 4096) + y * 64 + row0;
#pragma unroll
        for (int nt = 0; nt < 4; ++nt) {
            const int ch = nt * 16 + m_;
#pragma unroll
            for (int reg = 0; reg < 4; ++reg) {
                const size_t o = (base + q * 4 + reg) * 64 + ch;
                kout[o] = f2bf(ak[nt][reg]);
                vout[o] = f2bf(av[nt][reg]);
            }
        }
    }
}

// ---------------- slot init (+ rowsum zero) ----------------
__global__ __launch_bounds__(256) void slot_init(
    const float* __restrict__ noise, const float* __restrict__ init_slots,
    float* __restrict__ slots, float* __restrict__ rowsum)
{
    int i = blockIdx.x * 256 + threadIdx.x;
    if (i < 224) rowsum[i] = 0.f;
    if (i < 224 * 64) {
        int z = i & 63;
        float spl = log1pf(expf(init_slots[64 + z]));
        slots[i] = init_slots[z] + spl * noise[i];
    }
}

// ---------------- fused attention ----------------
__global__ __launch_bounds__(256) void attn_fused(
    const unsigned short* __restrict__ kbuf, const unsigned short* __restrict__ vbuf,
    const float* __restrict__ slots,
    const float* __restrict__ lnsg, const float* __restrict__ lnsb,
    const float* __restrict__ qw,
    float* __restrict__ part, float* __restrict__ rowsum)
{
    __shared__ float qs[7][64];
    __shared__ float ash[256][7];
    __shared__ float red7[7][4];
    __shared__ float redv[4][7][64];
    const int b = blockIdx.x >> 4;
    const int js = blockIdx.x & 15;
    const int j0 = js * 256;
    const int tid = threadIdx.x;
    const int lane = tid & 63, wv = tid >> 6;

    for (int i = wv; i < 7; i += 4) {
        float s = slots[(b * 7 + i) * 64 + lane];
        float m = wave_sum(s) * (1.f / 64.f);
        float d = s - m;
        float var = wave_sum(d * d) * (1.f / 64.f);
        float x = d * rsqrtf(var + 1e-5f) * lnsg[lane] + lnsb[lane];
        float qv = 0.f;
        for (int c = 0; c < 64; ++c) qv = fmaf(__shfl(x, c, 64), qw[c * 64 + lane], qv);
        qs[i][lane] = qv * SCALE_;
    }
    __syncthreads();

    {
        const int j = j0 + tid;
        float kr[64];
        const unsigned short* kp = kbuf + (((size_t)b * 4096) + j) * 64;
#pragma unroll
        for (int d8 = 0; d8 < 8; ++d8) {
            uint4 kv = ((const uint4*)kp)[d8];
            const unsigned short* h = (const unsigned short*)&kv;
#pragma unroll
            for (int z = 0; z < 8; ++z) kr[d8 * 8 + z] = bf2f(h[z]);
        }
        float dots[7];
#pragma unroll
        for (int i = 0; i < 7; ++i) {
            float a = 0.f;
#pragma unroll
            for (int d = 0; d < 64; ++d) a = fmaf(kr[d], qs[i][d], a);
            dots[i] = a;
        }
        float mx = dots[0];
#pragma unroll
        for (int i = 1; i < 7; ++i) mx = fmaxf(mx, dots[i]);
        float sum = 0.f;
#pragma unroll
        for (int i = 0; i < 7; ++i) { dots[i] = expf(dots[i] - mx); sum += dots[i]; }
        const float inv = 1.f / sum;
#pragma unroll
        for (int i = 0; i < 7; ++i) {
            float a = dots[i] * inv + 1e-8f;
            dots[i] = a;
            ash[tid][i] = a;
        }
#pragma unroll
        for (int i = 0; i < 7; ++i) {
            float s = wave_sum(dots[i]);
            if (lane == 0) red7[i][wv] = s;
        }
    }
    __syncthreads();
    if (tid < 7)
        atomicAdd(&rowsum[b * 7 + tid], red7[tid][0] + red7[tid][1] + red7[tid][2] + red7[tid][3]);

    {
        const int d = lane, jc = wv;
        float acc[7];
#pragma unroll
        for (int i = 0; i < 7; ++i) acc[i] = 0.f;
        for (int jl = jc; jl < 256; jl += 4) {
            float av = bf2f(vbuf[(((size_t)b * 4096) + j0 + jl) * 64 + d]);
#pragma unroll
            for (int i = 0; i < 7; ++i)
                acc[i] = fmaf(ash[jl][i], av, acc[i]);
        }
#pragma unroll
        for (int i = 0; i < 7; ++i) redv[jc][i][d] = acc[i];
    }
    __syncthreads();
    if (tid < 7 * 64) {
        int i = tid / 64, dd = tid % 64;
        float s = redv[0][i][dd] + redv[1][i][dd] + redv[2][i][dd] + redv[3][i][dd];
        part[((((size_t)b * 16) + js) * 7 + i) * 64 + dd] = s;
    }
}

// ---------------- GRU + residual MLP ----------------
__global__ __launch_bounds__(64) void gru_mlp(
    float* __restrict__ slots, const float* __restrict__ part,
    float* __restrict__ rowsum,
    const float* __restrict__ wih, const float* __restrict__ whh,
    const float* __restrict__ bih, const float* __restrict__ bhh,
    const float* __restrict__ lnfg, const float* __restrict__ lnfb,
    const float* __restrict__ m1w, const float* __restrict__ m1b,
    const float* __restrict__ m2w, const float* __restrict__ m2b)
{
    const int n = blockIdx.x;
    const int b = n / 7, i = n % 7;
    const int l = threadIdx.x;
    float upd = 0.f;
    for (int js = 0; js < 16; ++js)
        upd += part[((((size_t)b * 16) + js) * 7 + i) * 64 + l];
    upd /= rowsum[n];
    if (l == 0) rowsum[n] = 0.f;
    const float prev = slots[n * 64 + l];
    float gi0 = bih[l], gi1 = bih[64 + l], gi2 = bih[128 + l];
    float gh0 = bhh[l], gh1 = bhh[64 + l], gh2 = bhh[128 + l];
    for (int c = 0; c < 64; ++c) {
        float u = __shfl(upd, c, 64), p = __shfl(prev, c, 64);
        gi0 = fmaf(u, wih[l * 64 + c], gi0);
        gi1 = fmaf(u, wih[(64 + l) * 64 + c], gi1);
        gi2 = fmaf(u, wih[(128 + l) * 64 + c], gi2);
        gh0 = fmaf(p, whh[l * 64 + c], gh0);
        gh1 = fmaf(p, whh[(64 + l) * 64 + c], gh1);
        gh2 = fmaf(p, whh[(128 + l) * 64 + c], gh2);
    }
    float r  = 1.f / (1.f + expf(-(gi0 + gh0)));
    float zg = 1.f / (1.f + expf(-(gi1 + gh1)));
    float nn = tanhf(gi2 + r * gh2);
    float s = (1.f - zg) * nn + zg * prev;
    float m = wave_sum(s) * (1.f / 64.f);
    float d = s - m;
    float var = wave_sum(d * d) * (1.f / 64.f);
    float x = d * rsqrtf(var + 1e-5f) * lnfg[l] + lnfb[l];
    float h0 = m1b[l], h1 = m1b[64 + l];
    for (int c = 0; c < 64; ++c) {
        float xv = __shfl(x, c, 64);
        h0 = fmaf(xv, m1w[c * 128 + l], h0);
        h1 = fmaf(xv, m1w[c * 128 + 64 + l], h1);
    }
    h0 = fmaxf(h0, 0.f); h1 = fmaxf(h1, 0.f);
    float o = m2b[l];
    for (int c = 0; c < 64; ++c) {
        o = fmaf(__shfl(h0, c, 64), m2w[c * 64 + l], o);
        o = fmaf(__shfl(h1, c, 64), m2w[(64 + c) * 64 + l], o);
    }
    slots[n * 64 + l] = s + o;
}

// ---------------- finalize ----------------
__global__ __launch_bounds__(256) void finalize_k(
    const float* __restrict__ dc4out, const float* __restrict__ inputs,
    float* __restrict__ out)
{
    const int tid = threadIdx.x;
    const int gp = blockIdx.x * 256 + tid;
    const int b = gp >> 12, p = gp & 4095;
    float4 o4[7];
#pragma unroll
    for (int k = 0; k < 7; ++k)
        o4[k] = ((const float4*)dc4out)[(size_t)(b * 7 + k) * 4096 + p];
    float mx = o4[0].w;
#pragma unroll
    for (int k = 1; k < 7; ++k) mx = fmaxf(mx, o4[k].w);
    float s = 0.f;
#pragma unroll
    for (int k = 0; k < 7; ++k) s += expf(o4[k].w - mx);
    const float lse = mx + logf(s);
    float recon0 = 0.f, recon1 = 0.f, recon2 = 0.f;
    float* xl = out + 1;
    float* ml = out + 2752513;
#pragma unroll
    for (int k = 0; k < 7; ++k) {
        float lp = o4[k].w - lse;
        ml[((size_t)(b * 7 + k)) * 4096 + p] = lp;
        float w = expf(lp);
        float x0 = 1.f / (1.f + expf(-o4[k].x));
        float x1 = 1.f / (1.f + expf(-o4[k].y));
        float x2 = 1.f / (1.f + expf(-o4[k].z));
        xl[(((size_t)(b * 7 + k)) * 3 + 0) * 4096 + p] = x0;
        xl[(((size_t)(b * 7 + k)) * 3 + 1) * 4096 + p] = x1;
        xl[(((size_t)(b * 7 + k)) * 3 + 2) * 4096 + p] = x2;
        recon0 = fmaf(x0, w, recon0);
        recon1 = fmaf(x1, w, recon1);
        recon2 = fmaf(x2, w, recon2);
    }
    float err = 0.f;
    {
        float xo = (inputs[((size_t)b * 3 + 0) * 4096 + p] + 1.f) * 0.5f;
        float dd = xo - recon0; err += dd * dd;
        xo = (inputs[((size_t)b * 3 + 1) * 4096 + p] + 1.f) * 0.5f;
        dd = xo - recon1; err += dd * dd;
        xo = (inputs[((size_t)b * 3 + 2) * 4096 + p] + 1.f) * 0.5f;
        dd = xo - recon2; err += dd * dd;
    }
    float wsum = wave_sum(err);
    __shared__ float red[4];
    const int lane = tid & 63, wv = tid >> 6;
    if (lane == 0) red[wv] = wsum;
    __syncthreads();
    if (tid == 0) atomicAdd(out, (red[0] + red[1] + red[2] + red[3]) * (1.f / 32.f));
}

// ---------------- launch ----------------
extern "C" void kernel_launch(void* const* d_in, const int* in_sizes, int n_in,
                              void* d_out, int out_size, void* d_ws, size_t ws_size,
                              hipStream_t stream) {
    (void)in_sizes; (void)n_in; (void)out_size; (void)ws_size;
    const float* inputs = (const float*)d_in[0];
    const float* noise  = (const float*)d_in[1];
    const float* epw  = (const float*)d_in[2];
    const float* epb  = (const float*)d_in[3];
    const float* ec1w = (const float*)d_in[4];
    const float* ec1b = (const float*)d_in[5];
    const float* ec2w = (const float*)d_in[6];
    const float* ec2b = (const float*)d_in[7];
    const float* ec3w = (const float*)d_in[8];
    const float* ec3b = (const float*)d_in[9];
    const float* ec4w = (const float*)d_in[10];
    const float* ec4b = (const float*)d_in[11];
    const float* ln1g = (const float*)d_in[12];
    const float* ln1b = (const float*)d_in[13];
    const float* fc1w = (const float*)d_in[14];
    const float* fc1b = (const float*)d_in[15];
    const float* fc2w = (const float*)d_in[16];
    const float* fc2b = (const float*)d_in[17];
    const float* lnsg = (const float*)d_in[18];
    const float* lnsb = (const float*)d_in[19];
    const float* lnfg = (const float*)d_in[20];
    const float* lnfb = (const float*)d_in[21];
    const float* qw   = (const float*)d_in[22];
    const float* kw   = (const float*)d_in[23];
    const float* vw   = (const float*)d_in[24];
    const float* m1w  = (const float*)d_in[25];
    const float* m1b  = (const float*)d_in[26];
    const float* m2w  = (const float*)d_in[27];
    const float* m2b  = (const float*)d_in[28];
    const float* wih  = (const float*)d_in[29];
    const float* whh  = (const float*)d_in[30];
    const float* bih  = (const float*)d_in[31];
    const float* bhh  = (const float*)d_in[32];
    const float* init_slots = (const float*)d_in[33];
    const float* dpw  = (const float*)d_in[34];
    const float* dpb  = (const float*)d_in[35];
    const float* dc1w = (const float*)d_in[36];
    const float* dc1b = (const float*)d_in[37];
    const float* dc2w = (const float*)d_in[38];
    const float* dc2b = (const float*)d_in[39];
    const float* dc3w = (const float*)d_in[40];
    const float* dc3b = (const float*)d_in[41];
    const float* dc4w = (const float*)d_in[42];
    const float* dc4b = (const float*)d_in[43];

    float* ws = (float*)d_ws;
    unsigned short* B0 = (unsigned short*)(ws + WS_B0);
    unsigned short* B1 = (unsigned short*)(ws + WS_B1);
    unsigned short* K = (unsigned short*)(ws + WS_K);
    unsigned short* V = (unsigned short*)(ws + WS_V);
    unsigned short* dping = (unsigned short*)(ws + WS_B0);
    unsigned short* dpong = (unsigned short*)(ws + WS_K);
    float* dc4out = ws + WS_V;
    unsigned short* PK = (unsigned short*)(ws + WS_V + 4194304u);
    unsigned short* p_ec2 = PK, *p_ec3 = PK + 102400, *p_ec4 = PK + 204800;
    unsigned short* p_dc1 = PK, *p_dc2 = PK + 51200, *p_dc3 = PK + 76800, *p_dc4 = PK + 102400;
    float* attn  = ws + WS_ATTN;
    unsigned short* PFC = (unsigned short*)attn;
    unsigned short* p_fc1 = PFC;
    unsigned short* peb = (unsigned short*)(attn + OFF_PEB);
    float* wclsb = attn + OFF_WCLS;
    float* Sbuf  = attn + OFF_S;
    float* zbias = attn + OFF_ZB;
    float* part  = ws + WS_PART;
    float* P     = ws + WS_PART;
    float* zpage = ws + WS_ZP;
    float* slots = ws + WS_SLOT;
    float* rowsum = ws + WS_ROW;
    float* out = (float*)d_out;
    const unsigned short* zp16 = (const unsigned short*)zpage;

    // ---- pack encoder weights + fc mats + zero page (1 launch) ----
    pack_enc<<<159, 256, 0, stream>>>(ec2w, ec3w, ec4w, p_ec2,
                                      fc1w, fc2w, kw, vw, p_fc1, zpage);

    // ---- encoder ----
    conv_ec1<<<2048, 256, 0, stream>>>(inputs, ec1w, ec1b, B0);
    conv_mfma<64, 4, 2, 5, 2, 64, 1, 0><<<1024, 256, 0, stream>>>(B0, p_ec2, ec2b, B1, zp16, 64, 64, 64, 64, 4, 4);
    conv_mfma<64, 4, 2, 5, 2, 64, 1, 0><<<1024, 256, 0, stream>>>(B1, p_ec3, ec3b, B0, zp16, 64, 64, 64, 64, 4, 4);
    conv_mfma<64, 4, 2, 5, 2, 64, 1, 0><<<1024, 256, 0, stream>>>(B0, p_ec4, ec4b, B1, zp16, 64, 64, 64, 64, 4, 4);
    encoder_tail_mfma<<<2048, 256, 0, stream>>>(B1, epw, epb, ln1g, ln1b,
                                                p_fc1, fc1b, p_fc1 + 4096, fc2b,
                                                p_fc1 + 8192, p_fc1 + 12288, K, V);
    slot_init<<<56, 256, 0, stream>>>(noise, init_slots, slots, rowsum);

    // ---- 3 slot-attention iterations ----
    for (int it = 0; it < 3; ++it) {
        attn_fused<<<512, 256, 0, stream>>>(K, V, slots, lnsg, lnsb, qw, part, rowsum);
        gru_mlp<<<224, 64, 0, stream>>>(slots, part, rowsum, wih, whh, bih, bhh,
                                        lnfg, lnfb, m1w, m1b, m2w, m2b);
    }

    // ---- decoder prep (1 launch) + Wcls/S (2 tiny launches) ----
    dec_prep<<<128, 256, 0, stream>>>(dc1w, dc2w, dc3w, dc4w,
                                      p_dc1, p_dc2, p_dc3, p_dc4,
                                      dpw, dpb, peb, zbias, slots, out);
    wcls_build<<<72, 256, 0, stream>>>(dc1w, wclsb);
    slot_s<<<252, 256, 0, stream>>>(slots, wclsb, Sbuf);
    conv_mfma<64, 2, 2, 5, 1, 32, 0, 1><<<25, 256, 0, stream>>>(peb, p_dc1, zbias, P, zp16, 70, 70, 68, 68, 5, 5);

    // ---- decoder, 2 chunks of 112 images ----
    for (int ch = 0; ch < 2; ++ch) {
        float* d4o = dc4out + (size_t)ch * 112 * 4 * 4096;
        dc1_assemble<<<2023, 256, 0, stream>>>(P, Sbuf, dc1b, ch * 112, dping);
        conv_mfma<32, 2, 2, 5, 1, 32, 1, 0><<<2800, 256, 0, stream>>>(dping, p_dc2, dc2b, dpong, zp16, 68, 68, 66, 66, 5, 5);
        conv_mfma<32, 2, 2, 5, 1, 32, 1, 0><<<1792, 256, 0, stream>>>(dpong, p_dc3, dc3b, dping, zp16, 66, 66, 64, 64, 4, 4);
        conv_mfma<32, 1, 1, 3, 1, 4, 0, 1><<<1792, 256, 0, stream>>>(dping, p_dc4, dc4b, d4o, zp16, 64, 64, 64, 64, 4, 4);
    }

    // ---- outputs ----
    finalize_k<<<512, 256, 0, stream>>>(dc4out, inputs, out);
}

// Round 14
// 689.530 us; speedup vs baseline: 1.0409x; 1.0389x over previous
//
#include <hip/hip_runtime.h>
#include <math.h>

typedef short bf16x8 __attribute__((ext_vector_type(8)));
typedef float f32x4 __attribute__((ext_vector_type(4)));

// workspace layout (float offsets)
#define WS_B0   0u
#define WS_B1   4194304u
#define WS_K    8388608u
#define WS_V    16777216u
#define WS_ATTN 25165824u
#define WS_PART 26083328u
#define WS_ZP   26312704u
#define WS_SLOT 26327040u
#define WS_ROW  26341376u
#define SCALE_ 0.125f

// attn-region overlays (float offsets from attn base)
#define OFF_PEB   0u         // decode phase
#define OFF_QBUF  16384u     // attention phase: q [224][64] fp32
#define OFF_WIHT  32768u     // attention phase: wihT [64][192] fp32
#define OFF_WHHT  45056u     // attention phase: whhT [64][192] fp32
#define OFF_WCLS  160000u
#define OFF_S     180000u
#define OFF_ZB    250000u

__device__ __forceinline__ float wave_sum(float v) {
#pragma unroll
    for (int m = 32; m >= 1; m >>= 1) v += __shfl_xor(v, m, 64);
    return v;
}
__device__ __forceinline__ unsigned short f2bf(float f) {
    unsigned u = __float_as_uint(f);
    u = u + 0x7fffu + ((u >> 16) & 1u);
    return (unsigned short)(u >> 16);
}
__device__ __forceinline__ float bf2f(unsigned short h) {
    return __uint_as_float(((unsigned)h) << 16);
}
__device__ __forceinline__ void gl_lds16(const void* src, void* lds_base) {
    __builtin_amdgcn_global_load_lds(
        (const __attribute__((address_space(1))) unsigned int*)src,
        (__attribute__((address_space(3))) unsigned int*)lds_base,
        16, 0, 0);
}

// ---------------- weight packing (device helper, B-fragment order) ----------------
__device__ __forceinline__ void pack_one(
    const float* __restrict__ w, unsigned short* __restrict__ wp,
    int CIN, int COUT_STORE, int KS, int NT, int t)
{
    int lane = t & 63;
    int nt = (t >> 6) % NT;
    int ch = t / (64 * NT);
    int CPT = CIN / 32;
    int cic = ch % CPT;
    int tap = ch / CPT;
    int ky = tap / KS, kx = tap % KS;
    int co = nt * 16 + (lane & 15);
    int k0 = cic * 32 + (lane >> 4) * 8;
    unsigned short v[8];
#pragma unroll
    for (int j = 0; j < 8; ++j) {
        int ci = k0 + j;
        float f = (co < COUT_STORE) ? w[((size_t)(co * CIN + ci) * KS + ky) * KS + kx] : 0.f;
        v[j] = f2bf(f);
    }
    *(uint4*)(wp + (size_t)t * 8) = *(uint4*)v;
}

// ---------------- encoder-side packing: convs + fc mats + gru transposes + zero page ----------------
__global__ __launch_bounds__(256) void pack_enc(
    const float* __restrict__ ec2w, const float* __restrict__ ec3w,
    const float* __restrict__ ec4w, unsigned short* __restrict__ wp,
    const float* __restrict__ fc1w, const float* __restrict__ fc2w,
    const float* __restrict__ kw, const float* __restrict__ vw,
    unsigned short* __restrict__ pfc,
    const float* __restrict__ wih, const float* __restrict__ whh,
    float* __restrict__ wihT, float* __restrict__ whhT,
    float* __restrict__ zpage)
{
    if (blockIdx.x == 0 && threadIdx.x < 64) zpage[threadIdx.x] = 0.f;
    int t = blockIdx.x * 256 + threadIdx.x;
    if (t < 38400) {
        int which = t / 12800;
        int tt = t % 12800;
        const float* w = (which == 0) ? ec2w : ((which == 1) ? ec3w : ec4w);
        pack_one(w, wp + (size_t)which * 102400, 64, 64, 5, 4, tt);
        return;
    }
    t -= 38400;
    if (t < 2048) {
        int which = t / 512;
        int tt = t % 512;
        const float* w = (which == 0) ? fc1w : ((which == 1) ? fc2w : ((which == 2) ? kw : vw));
        unsigned short* dst = pfc + (size_t)which * 4096;
        int lane = tt & 63;
        int nt = (tt >> 6) & 3;
        int ck = tt >> 8;
        int n = nt * 16 + (lane & 15);
        int k0 = ck * 32 + (lane >> 4) * 8;
        unsigned short v[8];
#pragma unroll
        for (int j = 0; j < 8; ++j) v[j] = f2bf(w[(size_t)(k0 + j) * 64 + n]);
        *(uint4*)(dst + (size_t)tt * 8) = *(uint4*)v;
        return;
    }
    t -= 2048;
    if (t < 12288) {   // wihT[c*192 + j] = wih[j*64 + c]
        int c = t / 192, j = t % 192;
        wihT[t] = wih[(size_t)j * 64 + c];
        return;
    }
    t -= 12288;
    if (t < 12288) {
        int c = t / 192, j = t % 192;
        whhT[t] = whh[(size_t)j * 64 + c];
    }
}

// ---------------- decoder prep: packs + pe field + slot copy + zeroes ----------------
__global__ __launch_bounds__(256) void dec_prep(
    const float* __restrict__ dc1w, const float* __restrict__ dc2w,
    const float* __restrict__ dc3w, const float* __restrict__ dc4w,
    unsigned short* __restrict__ p_dc1, unsigned short* __restrict__ p_dc2,
    unsigned short* __restrict__ p_dc3, unsigned short* __restrict__ p_dc4,
    const float* __restrict__ dpw, const float* __restrict__ dpb,
    unsigned short* __restrict__ peb, float* __restrict__ zbias,
    const float* __restrict__ slots, float* __restrict__ out)
{
    int t = blockIdx.x * 256 + threadIdx.x;
    if (t < 6400) { pack_one(dc1w, p_dc1, 64, 32, 5, 2, t); return; }
    t -= 6400;
    if (t < 3200) { pack_one(dc2w, p_dc2, 32, 32, 5, 2, t); return; }
    t -= 3200;
    if (t < 3200) { pack_one(dc3w, p_dc3, 32, 32, 5, 2, t); return; }
    t -= 3200;
    if (t < 576)  { pack_one(dc4w, p_dc4, 32, 4, 3, 1, t); return; }
    t -= 576;
    if (t < 4900) {
        const int iy = t / 70, ix = t % 70;
        const float fy = iy * (1.f / 69.f), fx = ix * (1.f / 69.f);
        unsigned short v[64];
#pragma unroll
        for (int ci = 0; ci < 64; ++ci) {
            float p = (1.f - fy) * dpw[ci] + fy * dpw[64 + ci]
                    + fx * dpw[128 + ci] + (1.f - fx) * dpw[192 + ci] + dpb[ci];
            v[ci] = f2bf(p);
        }
        uint4* ob = (uint4*)(peb + (size_t)t * 64);
#pragma unroll
        for (int i = 0; i < 8; ++i) ob[i] = ((uint4*)v)[i];
        return;
    }
    t -= 4900;
    if (t < 14336) { out[3670017 + t] = slots[t]; return; }
    t -= 14336;
    if (t < 32) zbias[t] = 0.f;
    else if (t == 32) out[0] = 0.f;
}

// ---------------- Wcls[9][32][64] ----------------
__global__ __launch_bounds__(256) void wcls_build(
    const float* __restrict__ w, float* __restrict__ wcls)
{
    int idx = blockIdx.x * 256 + threadIdx.x;
    if (idx >= 9 * 32 * 64) return;
    int cls = idx / (32 * 64);
    int co = (idx / 64) % 32;
    int ci = idx % 64;
    int rc = cls / 3, cc = cls % 3;
    int ky0 = (rc == 0) ? 1 : 0, ky1 = (rc == 2) ? 3 : 4;
    int kx0 = (cc == 0) ? 1 : 0, kx1 = (cc == 2) ? 3 : 4;
    float s = 0.f;
    const float* wb = w + (size_t)(co * 64 + ci) * 25;
    for (int ky = ky0; ky <= ky1; ++ky)
        for (int kx = kx0; kx <= kx1; ++kx)
            s += wb[ky * 5 + kx];
    wcls[idx] = s;
}

// ---------------- S[224][9][32] = slots @ Wcls^T ----------------
__global__ __launch_bounds__(256) void slot_s(
    const float* __restrict__ slots, const float* __restrict__ wcls,
    float* __restrict__ S)
{
    int idx = blockIdx.x * 256 + threadIdx.x;
    if (idx >= 224 * 9 * 32) return;
    int n = idx / (9 * 32);
    int cls = (idx / 32) % 9;
    int co = idx % 32;
    const float* sl = slots + n * 64;
    const float* wc = wcls + (size_t)(cls * 32 + co) * 64;
    float s = 0.f;
#pragma unroll
    for (int ci = 0; ci < 64; ++ci) s = fmaf(sl[ci], wc[ci], s);
    S[idx] = s;
}

// ---------------- MFMA implicit-GEMM conv, async-DMA staged full-CIN tile (R11) ----------------
template<int CIN, int NTT, int NTU, int KS, int PAD, int NSTORE, int RELU, int OUTF32>
__global__ __launch_bounds__(256) void conv_mfma(
    const unsigned short* __restrict__ in, const unsigned short* __restrict__ wpack,
    const float* __restrict__ bias, void* __restrict__ outv,
    const unsigned short* __restrict__ zpage,
    int Hin, int Win, int Hout, int Wout, int tilesX, int tilesY)
{
    constexpr int TS = 16, TH = TS + KS - 1;
    constexpr int CPT = CIN / 32;
    constexpr int G8 = CIN / 8;
    constexpr int CS = NTT / NTU;
    constexpr int TOTCH = TH * TH * G8;
    constexpr int TOTCH_PAD = (TOTCH + 63) & ~63;
    __shared__ __align__(16) unsigned short tile[TOTCH_PAD * 8];
    const int tpb = tilesX * tilesY;
    const int blk = blockIdx.x;
    const int n = blk / (tpb * CS);
    const int rem = blk % (tpb * CS);
    const int t = rem / CS;
    const int cog = rem % CS;
    const int ntb = cog * NTU;
    const int ty0 = (t / tilesX) * TS, tx0 = (t % tilesX) * TS;
    const int tid = threadIdx.x;
    const int wv = tid >> 6, lane = tid & 63;

    const unsigned short* inb = in + (size_t)n * Hin * Win * CIN;
    for (int cb = wv * 64; cb < TOTCH; cb += 256) {
        const int idx = cb + lane;
        const int r = idx / (TH * G8);
        const int p = idx % (TH * G8);
        const int c = p / G8;
        const int chunk = p % G8;
        const int g = (chunk - c) & (G8 - 1);
        const int iy = ty0 - PAD + r, ix = tx0 - PAD + c;
        const bool ok = (idx < TOTCH) && ((unsigned)iy < (unsigned)Hin) && ((unsigned)ix < (unsigned)Win);
        const unsigned short* src = ok ? (inb + ((size_t)iy * Win + ix) * CIN + g * 8) : zpage;
        gl_lds16(src, tile + (size_t)cb * 8);
    }
    __syncthreads();

    const int q = lane >> 4, m = lane & 15;
    const int row0 = wv * 4;
    f32x4 acc[4][NTU];
#pragma unroll
    for (int mt = 0; mt < 4; ++mt)
#pragma unroll
        for (int nt = 0; nt < NTU; ++nt) acc[mt][nt] = (f32x4){0.f, 0.f, 0.f, 0.f};

#pragma unroll
    for (int cic = 0; cic < CPT; ++cic) {
#pragma unroll
        for (int kx = 0; kx < KS; ++kx) {
            bf16x8 B[KS][NTU];
#pragma unroll
            for (int ky = 0; ky < KS; ++ky)
#pragma unroll
                for (int nt = 0; nt < NTU; ++nt)
                    B[ky][nt] = *(const bf16x8*)(wpack +
                        ((size_t)(((ky * KS + kx) * CPT + cic) * NTT + ntb + nt) * 64 + lane) * 8);
            const int cbase = m + kx;
            const int slot = (cic * 32 + q * 8 + cbase * 8) % CIN;
#pragma unroll
            for (int ir = 0; ir < KS + 3; ++ir) {
                bf16x8 afr = *(const bf16x8*)&tile[((row0 + ir) * TH + cbase) * CIN + slot];
#pragma unroll
                for (int ky = 0; ky < KS; ++ky) {
                    const int mt = ir - ky;
                    if (mt < 0 || mt > 3) continue;
#pragma unroll
                    for (int nt = 0; nt < NTU; ++nt)
                        acc[mt][nt] = __builtin_amdgcn_mfma_f32_16x16x32_bf16(afr, B[ky][nt], acc[mt][nt], 0, 0, 0);
                }
            }
        }
    }

#pragma unroll
    for (int nt = 0; nt < NTU; ++nt) {
        const int co = (ntb + nt) * 16 + m;
        const float bv = (co < NSTORE) ? bias[co] : 0.f;
#pragma unroll
        for (int mt = 0; mt < 4; ++mt) {
            const int oy = ty0 + wv * 4 + mt;
#pragma unroll
            for (int j = 0; j < 4; ++j) {
                const int ox = tx0 + q * 4 + j;
                if (oy < Hout && ox < Wout && co < NSTORE) {
                    float v = acc[mt][nt][j] + bv;
                    if (RELU) v = fmaxf(v, 0.f);
                    size_t o = (((size_t)n * Hout + oy) * Wout + ox) * NSTORE + co;
                    if (OUTF32) ((float*)outv)[o] = v;
                    else ((unsigned short*)outv)[o] = f2bf(v);
                }
            }
        }
    }
}

// ---------------- dc1 assemble ----------------
__global__ __launch_bounds__(256) void dc1_assemble(
    const float* __restrict__ P, const float* __restrict__ S,
    const float* __restrict__ bias, int n0,
    unsigned short* __restrict__ out)
{
    const int gid = blockIdx.x * 256 + threadIdx.x;
    const int nl = gid / 4624;
    const int pix = gid % 4624;
    const int oy = pix / 68, ox = pix % 68;
    const int rc = (oy == 0) ? 0 : ((oy == 67) ? 2 : 1);
    const int cc = (ox == 0) ? 0 : ((ox == 67) ? 2 : 1);
    const float* Sp = S + ((size_t)(n0 + nl) * 9 + (rc * 3 + cc)) * 32;
    const float* Pp = P + (size_t)pix * 32;
    unsigned short v[32];
#pragma unroll
    for (int co = 0; co < 32; ++co)
        v[co] = f2bf(fmaxf(bias[co] + Pp[co] + Sp[co], 0.f));
    uint4* ob = (uint4*)(out + ((size_t)nl * 4624 + pix) * 32);
#pragma unroll
    for (int i = 0; i < 4; ++i) ob[i] = ((uint4*)v)[i];
}

// ---------------- encoder conv1 ----------------
__global__ __launch_bounds__(256) void conv_ec1(
    const float* __restrict__ in, const float* __restrict__ wts,
    const float* __restrict__ bias, unsigned short* __restrict__ out)
{
    __shared__ float tile[3][20][21];
    const int blk = blockIdx.x;
    const int n = blk >> 6;
    const int sub = blk & 63;
    const int t = sub >> 2;
    const int cog = sub & 3;
    const int ty0 = (t >> 2) * 16, tx0 = (t & 3) * 16;
    const int tid = threadIdx.x;
    for (int idx = tid; idx < 1200; idx += 256) {
        int ci = idx / 400, rc = idx % 400;
        int r = rc / 20, c = rc % 20;
        int gy = ty0 + r - 2, gx = tx0 + c - 2;
        float v = 0.f;
        if (gy >= 0 && gy < 64 && gx >= 0 && gx < 64)
            v = in[((size_t)n * 3 + ci) * 4096 + gy * 64 + gx];
        tile[ci][r][c] = v;
    }
    __syncthreads();
    const int lx = tid & 15, ly = tid >> 4;
    float acc[16];
#pragma unroll
    for (int co = 0; co < 16; ++co) acc[co] = bias[cog * 16 + co];
    for (int ci = 0; ci < 3; ++ci) {
        float val[25];
#pragma unroll
        for (int ky = 0; ky < 5; ++ky)
#pragma unroll
            for (int kx = 0; kx < 5; ++kx) val[ky * 5 + kx] = tile[ci][ly + ky][lx + kx];
#pragma unroll
        for (int co = 0; co < 16; ++co) {
            const float* wc = wts + (size_t)((cog * 16 + co) * 3 + ci) * 25;
            float a = acc[co];
#pragma unroll
            for (int tt = 0; tt < 25; ++tt) a = fmaf(val[tt], wc[tt], a);
            acc[co] = a;
        }
    }
    unsigned short tmp[16];
#pragma unroll
    for (int co = 0; co < 16; ++co) tmp[co] = f2bf(fmaxf(acc[co], 0.f));
    uint4* ob = (uint4*)(out + (((size_t)n * 64 + ty0 + ly) * 64 + tx0 + lx) * 64 + cog * 16);
    ob[0] = ((uint4*)tmp)[0];
    ob[1] = ((uint4*)tmp)[1];
}

// ---------------- encoder tail, MFMA (k/v out in bf16) ----------------
__global__ __launch_bounds__(256) void encoder_tail_mfma(
    const unsigned short* __restrict__ h4,
    const float* __restrict__ epw, const float* __restrict__ epb,
    const float* __restrict__ ln1g, const float* __restrict__ ln1b,
    const unsigned short* __restrict__ pfc1, const float* __restrict__ fc1b,
    const unsigned short* __restrict__ pfc2, const float* __restrict__ fc2b,
    const unsigned short* __restrict__ pkw, const unsigned short* __restrict__ pvw,
    unsigned short* __restrict__ kout, unsigned short* __restrict__ vout)
{
    __shared__ __align__(16) unsigned short X[64][72];
    const int b = blockIdx.x >> 6;
    const int y = blockIdx.x & 63;
    const int tid = threadIdx.x;

    {
        const int p = tid >> 2, sub = tid & 3;
        const unsigned short* hp = h4 + ((((size_t)b * 64 + y) * 64 + p) * 64) + sub * 16;
        unsigned short raw[16];
        *(uint4*)(raw)     = *(const uint4*)hp;
        *(uint4*)(raw + 8) = *(const uint4*)(hp + 8);
        const float fy = y * (1.f / 63.f), fx = p * (1.f / 63.f);
        float f[16];
        float s1 = 0.f, s2 = 0.f;
#pragma unroll
        for (int j = 0; j < 16; ++j) {
            int ch = sub * 16 + j;
            float pe = (1.f - fy) * epw[ch] + fy * epw[64 + ch]
                     + fx * epw[128 + ch] + (1.f - fx) * epw[192 + ch] + epb[ch];
            float v = bf2f(raw[j]) + pe;
            f[j] = v;
            s1 += v;
            s2 += v * v;
        }
        s1 += __shfl_xor(s1, 1, 64); s1 += __shfl_xor(s1, 2, 64);
        s2 += __shfl_xor(s2, 1, 64); s2 += __shfl_xor(s2, 2, 64);
        const float m = s1 * (1.f / 64.f);
        const float var = s2 * (1.f / 64.f) - m * m;
        const float inv = rsqrtf(var + 1e-5f);
        unsigned short xb[16];
#pragma unroll
        for (int j = 0; j < 16; ++j) {
            int ch = sub * 16 + j;
            xb[j] = f2bf((f[j] - m) * inv * ln1g[ch] + ln1b[ch]);
        }
        *(uint4*)&X[p][sub * 16]     = ((uint4*)xb)[0];
        *(uint4*)&X[p][sub * 16 + 8] = ((uint4*)xb)[1];
    }
    __syncthreads();

    const int w = tid >> 6, lane = tid & 63;
    const int q = lane >> 4, m_ = lane & 15;
    const int row0 = w * 16;

    {
        f32x4 a1[4];
#pragma unroll
        for (int nt = 0; nt < 4; ++nt) a1[nt] = (f32x4){0.f, 0.f, 0.f, 0.f};
#pragma unroll
        for (int ck = 0; ck < 2; ++ck) {
            bf16x8 afr = *(const bf16x8*)&X[row0 + m_][ck * 32 + q * 8];
#pragma unroll
            for (int nt = 0; nt < 4; ++nt) {
                bf16x8 bfr = *(const bf16x8*)(pfc1 + ((size_t)((ck * 4 + nt) * 64 + lane)) * 8);
                a1[nt] = __builtin_amdgcn_mfma_f32_16x16x32_bf16(afr, bfr, a1[nt], 0, 0, 0);
            }
        }
        __syncthreads();
#pragma unroll
        for (int nt = 0; nt < 4; ++nt) {
            const float bb = fc1b[nt * 16 + m_];
#pragma unroll
            for (int reg = 0; reg < 4; ++reg)
                X[row0 + q * 4 + reg][nt * 16 + m_] = f2bf(fmaxf(a1[nt][reg] + bb, 0.f));
        }
    }
    __syncthreads();

    {
        f32x4 a2[4];
#pragma unroll
        for (int nt = 0; nt < 4; ++nt) a2[nt] = (f32x4){0.f, 0.f, 0.f, 0.f};
#pragma unroll
        for (int ck = 0; ck < 2; ++ck) {
            bf16x8 afr = *(const bf16x8*)&X[row0 + m_][ck * 32 + q * 8];
#pragma unroll
            for (int nt = 0; nt < 4; ++nt) {
                bf16x8 bfr = *(const bf16x8*)(pfc2 + ((size_t)((ck * 4 + nt) * 64 + lane)) * 8);
                a2[nt] = __builtin_amdgcn_mfma_f32_16x16x32_bf16(afr, bfr, a2[nt], 0, 0, 0);
            }
        }
        __syncthreads();
#pragma unroll
        for (int nt = 0; nt < 4; ++nt) {
            const float bb = fc2b[nt * 16 + m_];
#pragma unroll
            for (int reg = 0; reg < 4; ++reg)
                X[row0 + q * 4 + reg][nt * 16 + m_] = f2bf(a2[nt][reg] + bb);
        }
    }
    __syncthreads();

    {
        f32x4 ak[4], av[4];
#pragma unroll
        for (int nt = 0; nt < 4; ++nt) {
            ak[nt] = (f32x4){0.f, 0.f, 0.f, 0.f};
            av[nt] = (f32x4){0.f, 0.f, 0.f, 0.f};
        }
#pragma unroll
        for (int ck = 0; ck < 2; ++ck) {
            bf16x8 afr = *(const bf16x8*)&X[row0 + m_][ck * 32 + q * 8];
#pragma unroll
            for (int nt = 0; nt < 4; ++nt) {
                bf16x8 bk = *(const bf16x8*)(pkw + ((size_t)((ck * 4 + nt) * 64 + lane)) * 8);
                bf16x8 bv = *(const bf16x8*)(pvw + ((size_t)((ck * 4 + nt) * 64 + lane)) * 8);
                ak[nt] = __builtin_amdgcn_mfma_f32_16x16x32_bf16(afr, bk, ak[nt], 0, 0, 0);
                av[nt] = __builtin_amdgcn_mfma_f32_16x16x32_bf16(afr, bv, av[nt], 0, 0, 0);
            }
        }
        const size_t base = ((size_t)b * 4096) + y * 64 + row0;
#pragma unroll
        for (int nt = 0; nt < 4; ++nt) {
            const int ch = nt * 16 + m_;
#pragma unroll
            for (int reg = 0; reg < 4; ++reg) {
                const size_t o = (base + q * 4 + reg) * 64 + ch;
                kout[o] = f2bf(ak[nt][reg]);
                vout[o] = f2bf(av[nt][reg]);
            }
        }
    }
}

// ---------------- slot init (+ rowsum zero) ----------------
__global__ __launch_bounds__(256) void slot_init(
    const float* __restrict__ noise, const float* __restrict__ init_slots,
    float* __restrict__ slots, float* __restrict__ rowsum)
{
    int i = blockIdx.x * 256 + threadIdx.x;
    if (i < 224) rowsum[i] = 0.f;
    if (i < 224 * 64) {
        int z = i & 63;
        float spl = log1pf(expf(init_slots[64 + z]));
        slots[i] = init_slots[z] + spl * noise[i];
    }
}

// ---------------- q0 = LN(slots)@qw * scale (wave per slot) ----------------
__global__ __launch_bounds__(256) void compute_q0(
    const float* __restrict__ slots, const float* __restrict__ lnsg,
    const float* __restrict__ lnsb, const float* __restrict__ qw,
    float* __restrict__ qbuf)
{
    const int n = blockIdx.x * 4 + (threadIdx.x >> 6);
    const int l = threadIdx.x & 63;
    if (n >= 224) return;
    float s = slots[n * 64 + l];
    float m = wave_sum(s) * (1.f / 64.f);
    float d = s - m;
    float var = wave_sum(d * d) * (1.f / 64.f);
    float x = d * rsqrtf(var + 1e-5f) * lnsg[l] + lnsb[l];
    float qv = 0.f;
    for (int c = 0; c < 64; ++c) qv = fmaf(__shfl(x, c, 64), qw[c * 64 + l], qv);
    qbuf[n * 64 + l] = qv * SCALE_;
}

// ---------------- fused attention (q precomputed in qbuf) ----------------
__global__ __launch_bounds__(256) void attn_fused(
    const unsigned short* __restrict__ kbuf, const unsigned short* __restrict__ vbuf,
    const float* __restrict__ qbuf,
    float* __restrict__ part, float* __restrict__ rowsum)
{
    __shared__ float qs[7][64];
    __shared__ float ash[256][7];
    __shared__ float red7[7][4];
    __shared__ float redv[4][7][64];
    const int b = blockIdx.x >> 4;
    const int js = blockIdx.x & 15;
    const int j0 = js * 256;
    const int tid = threadIdx.x;
    const int lane = tid & 63, wv = tid >> 6;

    if (tid < 448) qs[tid / 64][tid & 63] = qbuf[b * 448 + tid];
    __syncthreads();

    {
        const int j = j0 + tid;
        float kr[64];
        const unsigned short* kp = kbuf + (((size_t)b * 4096) + j) * 64;
#pragma unroll
        for (int d8 = 0; d8 < 8; ++d8) {
            uint4 kv = ((const uint4*)kp)[d8];
            const unsigned short* h = (const unsigned short*)&kv;
#pragma unroll
            for (int z = 0; z < 8; ++z) kr[d8 * 8 + z] = bf2f(h[z]);
        }
        float dots[7];
#pragma unroll
        for (int i = 0; i < 7; ++i) {
            float a = 0.f;
#pragma unroll
            for (int d = 0; d < 64; ++d) a = fmaf(kr[d], qs[i][d], a);
            dots[i] = a;
        }
        float mx = dots[0];
#pragma unroll
        for (int i = 1; i < 7; ++i) mx = fmaxf(mx, dots[i]);
        float sum = 0.f;
#pragma unroll
        for (int i = 0; i < 7; ++i) { dots[i] = expf(dots[i] - mx); sum += dots[i]; }
        const float inv = 1.f / sum;
#pragma unroll
        for (int i = 0; i < 7; ++i) {
            float a = dots[i] * inv + 1e-8f;
            dots[i] = a;
            ash[tid][i] = a;
        }
#pragma unroll
        for (int i = 0; i < 7; ++i) {
            float s = wave_sum(dots[i]);
            if (lane == 0) red7[i][wv] = s;
        }
    }
    __syncthreads();
    if (tid < 7)
        atomicAdd(&rowsum[b * 7 + tid], red7[tid][0] + red7[tid][1] + red7[tid][2] + red7[tid][3]);

    {
        const int d = lane, jc = wv;
        float acc[7];
#pragma unroll
        for (int i = 0; i < 7; ++i) acc[i] = 0.f;
        for (int jl = jc; jl < 256; jl += 4) {
            float av = bf2f(vbuf[(((size_t)b * 4096) + j0 + jl) * 64 + d]);
#pragma unroll
            for (int i = 0; i < 7; ++i)
                acc[i] = fmaf(ash[jl][i], av, acc[i]);
        }
#pragma unroll
        for (int i = 0; i < 7; ++i) redv[jc][i][d] = acc[i];
    }
    __syncthreads();
    if (tid < 7 * 64) {
        int i = tid / 64, dd = tid % 64;
        float s = redv[0][i][dd] + redv[1][i][dd] + redv[2][i][dd] + redv[3][i][dd];
        part[((((size_t)b * 16) + js) * 7 + i) * 64 + dd] = s;
    }
}

// ---------------- GRU + residual MLP (coalesced wihT/whhT; emits next q) ----------------
__global__ __launch_bounds__(64) void gru_mlp(
    float* __restrict__ slots, const float* __restrict__ part,
    float* __restrict__ rowsum,
    const float* __restrict__ wihT, const float* __restrict__ whhT,
    const float* __restrict__ bih, const float* __restrict__ bhh,
    const float* __restrict__ lnfg, const float* __restrict__ lnfb,
    const float* __restrict__ m1w, const float* __restrict__ m1b,
    const float* __restrict__ m2w, const float* __restrict__ m2b,
    const float* __restrict__ lnsg, const float* __restrict__ lnsb,
    const float* __restrict__ qw, float* __restrict__ qbuf)
{
    const int n = blockIdx.x;
    const int b = n / 7, i = n % 7;
    const int l = threadIdx.x;
    float upd = 0.f;
    for (int js = 0; js < 16; ++js)
        upd += part[((((size_t)b * 16) + js) * 7 + i) * 64 + l];
    upd /= rowsum[n];
    if (l == 0) rowsum[n] = 0.f;
    const float prev = slots[n * 64 + l];
    float gi0 = bih[l], gi1 = bih[64 + l], gi2 = bih[128 + l];
    float gh0 = bhh[l], gh1 = bhh[64 + l], gh2 = bhh[128 + l];
    for (int c = 0; c < 64; ++c) {
        float u = __shfl(upd, c, 64), p = __shfl(prev, c, 64);
        const float* wi = wihT + c * 192;
        const float* wh = whhT + c * 192;
        gi0 = fmaf(u, wi[l], gi0);
        gi1 = fmaf(u, wi[64 + l], gi1);
        gi2 = fmaf(u, wi[128 + l], gi2);
        gh0 = fmaf(p, wh[l], gh0);
        gh1 = fmaf(p, wh[64 + l], gh1);
        gh2 = fmaf(p, wh[128 + l], gh2);
    }
    float r  = 1.f / (1.f + expf(-(gi0 + gh0)));
    float zg = 1.f / (1.f + expf(-(gi1 + gh1)));
    float nn = tanhf(gi2 + r * gh2);
    float s = (1.f - zg) * nn + zg * prev;
    float m = wave_sum(s) * (1.f / 64.f);
    float d = s - m;
    float var = wave_sum(d * d) * (1.f / 64.f);
    float x = d * rsqrtf(var + 1e-5f) * lnfg[l] + lnfb[l];
    float h0 = m1b[l], h1 = m1b[64 + l];
    for (int c = 0; c < 64; ++c) {
        float xv = __shfl(x, c, 64);
        h0 = fmaf(xv, m1w[c * 128 + l], h0);
        h1 = fmaf(xv, m1w[c * 128 + 64 + l], h1);
    }
    h0 = fmaxf(h0, 0.f); h1 = fmaxf(h1, 0.f);
    float o = m2b[l];
    for (int c = 0; c < 64; ++c) {
        o = fmaf(__shfl(h0, c, 64), m2w[c * 64 + l], o);
        o = fmaf(__shfl(h1, c, 64), m2w[(64 + c) * 64 + l], o);
    }
    const float sv = s + o;
    slots[n * 64 + l] = sv;
    // next iteration's q = LN(sv) @ qw * scale
    float mq = wave_sum(sv) * (1.f / 64.f);
    float dq = sv - mq;
    float vq = wave_sum(dq * dq) * (1.f / 64.f);
    float xq = dq * rsqrtf(vq + 1e-5f) * lnsg[l] + lnsb[l];
    float qv = 0.f;
    for (int c = 0; c < 64; ++c) qv = fmaf(__shfl(xq, c, 64), qw[c * 64 + l], qv);
    qbuf[n * 64 + l] = qv * SCALE_;
}

// ---------------- finalize ----------------
__global__ __launch_bounds__(256) void finalize_k(
    const float* __restrict__ dc4out, const float* __restrict__ inputs,
    float* __restrict__ out)
{
    const int tid = threadIdx.x;
    const int gp = blockIdx.x * 256 + tid;
    const int b = gp >> 12, p = gp & 4095;
    float4 o4[7];
#pragma unroll
    for (int k = 0; k < 7; ++k)
        o4[k] = ((const float4*)dc4out)[(size_t)(b * 7 + k) * 4096 + p];
    float mx = o4[0].w;
#pragma unroll
    for (int k = 1; k < 7; ++k) mx = fmaxf(mx, o4[k].w);
    float s = 0.f;
#pragma unroll
    for (int k = 0; k < 7; ++k) s += expf(o4[k].w - mx);
    const float lse = mx + logf(s);
    float recon0 = 0.f, recon1 = 0.f, recon2 = 0.f;
    float* xl = out + 1;
    float* ml = out + 2752513;
#pragma unroll
    for (int k = 0; k < 7; ++k) {
        float lp = o4[k].w - lse;
        ml[((size_t)(b * 7 + k)) * 4096 + p] = lp;
        float w = expf(lp);
        float x0 = 1.f / (1.f + expf(-o4[k].x));
        float x1 = 1.f / (1.f + expf(-o4[k].y));
        float x2 = 1.f / (1.f + expf(-o4[k].z));
        xl[(((size_t)(b * 7 + k)) * 3 + 0) * 4096 + p] = x0;
        xl[(((size_t)(b * 7 + k)) * 3 + 1) * 4096 + p] = x1;
        xl[(((size_t)(b * 7 + k)) * 3 + 2) * 4096 + p] = x2;
        recon0 = fmaf(x0, w, recon0);
        recon1 = fmaf(x1, w, recon1);
        recon2 = fmaf(x2, w, recon2);
    }
    float err = 0.f;
    {
        float xo = (inputs[((size_t)b * 3 + 0) * 4096 + p] + 1.f) * 0.5f;
        float dd = xo - recon0; err += dd * dd;
        xo = (inputs[((size_t)b * 3 + 1) * 4096 + p] + 1.f) * 0.5f;
        dd = xo - recon1; err += dd * dd;
        xo = (inputs[((size_t)b * 3 + 2) * 4096 + p] + 1.f) * 0.5f;
        dd = xo - recon2; err += dd * dd;
    }
    float wsum = wave_sum(err);
    __shared__ float red[4];
    const int lane = tid & 63, wv = tid >> 6;
    if (lane == 0) red[wv] = wsum;
    __syncthreads();
    if (tid == 0) atomicAdd(out, (red[0] + red[1] + red[2] + red[3]) * (1.f / 32.f));
}

// ---------------- launch ----------------
extern "C" void kernel_launch(void* const* d_in, const int* in_sizes, int n_in,
                              void* d_out, int out_size, void* d_ws, size_t ws_size,
                              hipStream_t stream) {
    (void)in_sizes; (void)n_in; (void)out_size; (void)ws_size;
    const float* inputs = (const float*)d_in[0];
    const float* noise  = (const float*)d_in[1];
    const float* epw  = (const float*)d_in[2];
    const float* epb  = (const float*)d_in[3];
    const float* ec1w = (const float*)d_in[4];
    const float* ec1b = (const float*)d_in[5];
    const float* ec2w = (const float*)d_in[6];
    const float* ec2b = (const float*)d_in[7];
    const float* ec3w = (const float*)d_in[8];
    const float* ec3b = (const float*)d_in[9];
    const float* ec4w = (const float*)d_in[10];
    const float* ec4b = (const float*)d_in[11];
    const float* ln1g = (const float*)d_in[12];
    const float* ln1b = (const float*)d_in[13];
    const float* fc1w = (const float*)d_in[14];
    const float* fc1b = (const float*)d_in[15];
    const float* fc2w = (const float*)d_in[16];
    const float* fc2b = (const float*)d_in[17];
    const float* lnsg = (const float*)d_in[18];
    const float* lnsb = (const float*)d_in[19];
    const float* lnfg = (const float*)d_in[20];
    const float* lnfb = (const float*)d_in[21];
    const float* qw   = (const float*)d_in[22];
    const float* kw   = (const float*)d_in[23];
    const float* vw   = (const float*)d_in[24];
    const float* m1w  = (const float*)d_in[25];
    const float* m1b  = (const float*)d_in[26];
    const float* m2w  = (const float*)d_in[27];
    const float* m2b  = (const float*)d_in[28];
    const float* wih  = (const float*)d_in[29];
    const float* whh  = (const float*)d_in[30];
    const float* bih  = (const float*)d_in[31];
    const float* bhh  = (const float*)d_in[32];
    const float* init_slots = (const float*)d_in[33];
    const float* dpw  = (const float*)d_in[34];
    const float* dpb  = (const float*)d_in[35];
    const float* dc1w = (const float*)d_in[36];
    const float* dc1b = (const float*)d_in[37];
    const float* dc2w = (const float*)d_in[38];
    const float* dc2b = (const float*)d_in[39];
    const float* dc3w = (const float*)d_in[40];
    const float* dc3b = (const float*)d_in[41];
    const float* dc4w = (const float*)d_in[42];
    const float* dc4b = (const float*)d_in[43];

    float* ws = (float*)d_ws;
    unsigned short* B0 = (unsigned short*)(ws + WS_B0);
    unsigned short* B1 = (unsigned short*)(ws + WS_B1);
    unsigned short* K = (unsigned short*)(ws + WS_K);
    unsigned short* V = (unsigned short*)(ws + WS_V);
    unsigned short* dping = (unsigned short*)(ws + WS_B0);
    unsigned short* dpong = (unsigned short*)(ws + WS_K);
    float* dc4out = ws + WS_V;
    unsigned short* PK = (unsigned short*)(ws + WS_V + 4194304u);
    unsigned short* p_ec2 = PK, *p_ec3 = PK + 102400, *p_ec4 = PK + 204800;
    unsigned short* p_dc1 = PK, *p_dc2 = PK + 51200, *p_dc3 = PK + 76800, *p_dc4 = PK + 102400;
    float* attn  = ws + WS_ATTN;
    unsigned short* PFC = (unsigned short*)attn;
    unsigned short* p_fc1 = PFC;
    unsigned short* peb = (unsigned short*)(attn + OFF_PEB);
    float* qbuf  = attn + OFF_QBUF;
    float* wihT  = attn + OFF_WIHT;
    float* whhT  = attn + OFF_WHHT;
    float* wclsb = attn + OFF_WCLS;
    float* Sbuf  = attn + OFF_S;
    float* zbias = attn + OFF_ZB;
    float* part  = ws + WS_PART;
    float* P     = ws + WS_PART;
    float* zpage = ws + WS_ZP;
    float* slots = ws + WS_SLOT;
    float* rowsum = ws + WS_ROW;
    float* out = (float*)d_out;
    const unsigned short* zp16 = (const unsigned short*)zpage;

    // ---- pack encoder weights + fc mats + gru transposes + zero page (1 launch) ----
    pack_enc<<<254, 256, 0, stream>>>(ec2w, ec3w, ec4w, p_ec2,
                                      fc1w, fc2w, kw, vw, p_fc1,
                                      wih, whh, wihT, whhT, zpage);

    // ---- encoder ----
    conv_ec1<<<2048, 256, 0, stream>>>(inputs, ec1w, ec1b, B0);
    conv_mfma<64, 4, 2, 5, 2, 64, 1, 0><<<1024, 256, 0, stream>>>(B0, p_ec2, ec2b, B1, zp16, 64, 64, 64, 64, 4, 4);
    conv_mfma<64, 4, 2, 5, 2, 64, 1, 0><<<1024, 256, 0, stream>>>(B1, p_ec3, ec3b, B0, zp16, 64, 64, 64, 64, 4, 4);
    conv_mfma<64, 4, 2, 5, 2, 64, 1, 0><<<1024, 256, 0, stream>>>(B0, p_ec4, ec4b, B1, zp16, 64, 64, 64, 64, 4, 4);
    encoder_tail_mfma<<<2048, 256, 0, stream>>>(B1, epw, epb, ln1g, ln1b,
                                                p_fc1, fc1b, p_fc1 + 4096, fc2b,
                                                p_fc1 + 8192, p_fc1 + 12288, K, V);
    slot_init<<<56, 256, 0, stream>>>(noise, init_slots, slots, rowsum);
    compute_q0<<<56, 256, 0, stream>>>(slots, lnsg, lnsb, qw, qbuf);

    // ---- 3 slot-attention iterations ----
    for (int it = 0; it < 3; ++it) {
        attn_fused<<<512, 256, 0, stream>>>(K, V, qbuf, part, rowsum);
        gru_mlp<<<224, 64, 0, stream>>>(slots, part, rowsum, wihT, whhT, bih, bhh,
                                        lnfg, lnfb, m1w, m1b, m2w, m2b,
                                        lnsg, lnsb, qw, qbuf);
    }

    // ---- decoder prep (1 launch) + Wcls/S (2 tiny launches) ----
    dec_prep<<<128, 256, 0, stream>>>(dc1w, dc2w, dc3w, dc4w,
                                      p_dc1, p_dc2, p_dc3, p_dc4,
                                      dpw, dpb, peb, zbias, slots, out);
    wcls_build<<<72, 256, 0, stream>>>(dc1w, wclsb);
    slot_s<<<252, 256, 0, stream>>>(slots, wclsb, Sbuf);
    conv_mfma<64, 2, 2, 5, 1, 32, 0, 1><<<25, 256, 0, stream>>>(peb, p_dc1, zbias, P, zp16, 70, 70, 68, 68, 5, 5);

    // ---- decoder, 2 chunks of 112 images ----
    for (int ch = 0; ch < 2; ++ch) {
        float* d4o = dc4out + (size_t)ch * 112 * 4 * 4096;
        dc1_assemble<<<2023, 256, 0, stream>>>(P, Sbuf, dc1b, ch * 112, dping);
        conv_mfma<32, 2, 2, 5, 1, 32, 1, 0><<<2800, 256, 0, stream>>>(dping, p_dc2, dc2b, dpong, zp16, 68, 68, 66, 66, 5, 5);
        conv_mfma<32, 2, 2, 5, 1, 32, 1, 0><<<1792, 256, 0, stream>>>(dpong, p_dc3, dc3b, dping, zp16, 66, 66, 64, 64, 4, 4);
        conv_mfma<32, 1, 1, 3, 1, 4, 0, 1><<<1792, 256, 0, stream>>>(dping, p_dc4, dc4b, d4o, zp16, 64, 64, 64, 64, 4, 4);
    }

    // ---- outputs ----
    finalize_k<<<512, 256, 0, stream>>>(dc4out, inputs, out);
}